// Round 1
// baseline (6789.886 us; speedup 1.0000x reference)
//
#include <hip/hip_runtime.h>
#include <float.h>

#define BB 8
#define NN 2048
#define KNN 20

// ---------- transpose x (B,3,N) -> xt (B,N,3) ----------
__global__ void k_transpose_x(const float* __restrict__ x, float* __restrict__ xt) {
    int i = blockIdx.x * 256 + threadIdx.x;
    if (i >= BB * NN * 3) return;
    int c = i % 3; int n = (i / 3) % NN; int b = i / (3 * NN);
    xt[i] = x[((size_t)b * 3 + c) * NN + n];
}

// ---------- transpose w (CO,CI) -> wt (CI,CO) ----------
__global__ void k_transpose_w(const float* __restrict__ w, float* __restrict__ wt, int CO, int CI) {
    int i = blockIdx.x * 256 + threadIdx.x;
    if (i >= CO * CI) return;
    int o = i / CI, c = i % CI;
    wt[c * CO + o] = w[i];
}

// ---------- squared norms per point ----------
template<int C>
__global__ void k_xx(const float* __restrict__ F, int FS, float* __restrict__ xx) {
    int i = blockIdx.x * 256 + threadIdx.x;
    if (i >= BB * NN) return;
    const float* r = F + (size_t)i * FS;
    float s = 0.f;
    #pragma unroll
    for (int c = 0; c < C; ++c) { float v = r[c]; s += v * v; }
    xx[i] = s;
}

// ---------- KNN: one block per query point ----------
template<int C>
__global__ void k_knn(const float* __restrict__ F, int FS, const float* __restrict__ xx,
                      int* __restrict__ idx) {
    __shared__ float q[C];
    __shared__ float dist[NN];
    __shared__ float rv[256];
    __shared__ int   ri[256];
    int bn = blockIdx.x;          // b*N + n
    int b = bn / NN;
    int tid = threadIdx.x;
    const float* Fb = F + (size_t)b * NN * FS;
    const float* qrow = F + (size_t)bn * FS;
    for (int c = tid; c < C; c += 256) q[c] = qrow[c];
    __syncthreads();
    float xxn = xx[bn];
    for (int m = tid; m < NN; m += 256) {
        const float* pr = Fb + (size_t)m * FS;
        float dot = 0.f;
        #pragma unroll
        for (int c = 0; c < C; ++c) dot += q[c] * pr[c];
        dist[m] = 2.f * dot - xxn - xx[b * NN + m];
    }
    __syncthreads();
    for (int k = 0; k < KNN; ++k) {
        float bv = -FLT_MAX; int bi = NN;
        for (int m = tid; m < NN; m += 256) {
            float v = dist[m];
            if (v > bv || (v == bv && m < bi)) { bv = v; bi = m; }
        }
        rv[tid] = bv; ri[tid] = bi;
        __syncthreads();
        for (int s = 128; s > 0; s >>= 1) {
            if (tid < s) {
                float v2 = rv[tid + s]; int i2 = ri[tid + s];
                if (v2 > rv[tid] || (v2 == rv[tid] && i2 < ri[tid])) { rv[tid] = v2; ri[tid] = i2; }
            }
            __syncthreads();
        }
        if (tid == 0) {
            int w = ri[0];
            idx[(size_t)bn * KNN + k] = w;
            dist[w] = -FLT_MAX;
        }
        __syncthreads();
    }
}

// ---------- EdgeConv: h[o,k] = dot(nbr_k, wA_o) + dot(center, wB_o - wA_o); leaky; max_k ----------
template<int CIN, int COUT, int NPT>
__global__ void k_edgeconv(const float* __restrict__ F, int FS,
                           const int* __restrict__ idx,
                           const float* __restrict__ wt,   // (2*CIN, COUT) transposed
                           const float* __restrict__ sc, const float* __restrict__ bi,
                           float* __restrict__ out, int OS) {
    __shared__ float ctr[NPT][CIN];
    __shared__ float nbr[NPT][KNN][CIN];
    int blk = blockIdx.x;
    int tilesPerB = NN / NPT;
    int b = blk / tilesPerB;
    int n0 = (blk % tilesPerB) * NPT;
    int tid = threadIdx.x;
    const float* Fb = F + (size_t)b * NN * FS;
    for (int i = tid; i < NPT * CIN; i += 256) {
        int p = i / CIN, c = i % CIN;
        ctr[p][c] = Fb[(size_t)(n0 + p) * FS + c];
    }
    for (int i = tid; i < NPT * KNN * CIN; i += 256) {
        int c = i % CIN; int k = (i / CIN) % KNN; int p = i / (CIN * KNN);
        int m = idx[((size_t)b * NN + n0 + p) * KNN + k];
        nbr[p][k][c] = Fb[(size_t)m * FS + c];
    }
    __syncthreads();
    for (int pair = tid; pair < NPT * COUT; pair += 256) {
        int o = pair % COUT, p = pair / COUT;
        float ct = 0.f;
        for (int c = 0; c < CIN; ++c)
            ct += ctr[p][c] * (wt[(CIN + c) * COUT + o] - wt[c * COUT + o]);
        float acc[KNN];
        #pragma unroll
        for (int k = 0; k < KNN; ++k) acc[k] = ct;
        for (int c = 0; c < CIN; ++c) {
            float wv = wt[c * COUT + o];
            #pragma unroll
            for (int k = 0; k < KNN; ++k) acc[k] += nbr[p][k][c] * wv;
        }
        float sv = sc[o], bv = bi[o];
        float mx = -FLT_MAX;
        #pragma unroll
        for (int k = 0; k < KNN; ++k) {
            float h = acc[k] * sv + bv;
            h = h >= 0.f ? h : 0.2f * h;
            mx = fmaxf(mx, h);
        }
        out[((size_t)b * NN + n0 + p) * OS + o] = mx;
    }
}

// ---------- conv5 (512 -> 1024) fused with partial max/mean pooling ----------
#define NT5 16
__global__ void k_conv5pool(const float* __restrict__ xcat,
                            const float* __restrict__ w5t,  // (512,1024)
                            const float* __restrict__ s5, const float* __restrict__ b5,
                            float* __restrict__ pmax, float* __restrict__ psum) {
    __shared__ float xr[NT5 * 512];
    int blk = blockIdx.x;
    int chunks = NN / NT5;            // 128
    int b = blk / chunks;
    int ch = blk % chunks;
    int n0 = ch * NT5;
    int tid = threadIdx.x;
    const float* base = xcat + ((size_t)b * NN + n0) * 512;
    for (int i = tid; i < NT5 * 512; i += 256) xr[i] = base[i];
    __syncthreads();
    float acc[NT5][4];
    #pragma unroll
    for (int p = 0; p < NT5; ++p)
        #pragma unroll
        for (int j = 0; j < 4; ++j) acc[p][j] = 0.f;
    for (int c = 0; c < 512; ++c) {
        float w0 = w5t[(size_t)c * 1024 + tid];
        float w1 = w5t[(size_t)c * 1024 + tid + 256];
        float w2 = w5t[(size_t)c * 1024 + tid + 512];
        float w3 = w5t[(size_t)c * 1024 + tid + 768];
        #pragma unroll
        for (int p = 0; p < NT5; ++p) {
            float xv = xr[p * 512 + c];
            acc[p][0] += xv * w0; acc[p][1] += xv * w1;
            acc[p][2] += xv * w2; acc[p][3] += xv * w3;
        }
    }
    #pragma unroll
    for (int j = 0; j < 4; ++j) {
        int o = tid + 256 * j;
        float sv = s5[o], bv = b5[o];
        float mx = -FLT_MAX, sm = 0.f;
        #pragma unroll
        for (int p = 0; p < NT5; ++p) {
            float h = acc[p][j] * sv + bv;
            h = h >= 0.f ? h : 0.2f * h;
            mx = fmaxf(mx, h); sm += h;
        }
        pmax[((size_t)b * chunks + ch) * 1024 + o] = mx;
        psum[((size_t)b * chunks + ch) * 1024 + o] = sm;
    }
}

__global__ void k_poolreduce(const float* __restrict__ pmax, const float* __restrict__ psum,
                             float* __restrict__ pooled) {
    int i = blockIdx.x * 256 + threadIdx.x;   // b*1024 + o
    if (i >= BB * 1024) return;
    int b = i / 1024, o = i % 1024;
    int chunks = NN / NT5;
    float mx = -FLT_MAX, sm = 0.f;
    for (int ch = 0; ch < chunks; ++ch) {
        mx = fmaxf(mx, pmax[((size_t)b * chunks + ch) * 1024 + o]);
        sm += psum[((size_t)b * chunks + ch) * 1024 + o];
    }
    pooled[(size_t)b * 2048 + o] = mx;
    pooled[(size_t)b * 2048 + 1024 + o] = sm / (float)NN;
}

// ---------- FC: out[b][o] = act(dot(in[b], w[o]) * s[o] + bias[o]) ----------
__global__ void k_fc(const float* __restrict__ in, const float* __restrict__ w,
                     const float* __restrict__ sc, const float* __restrict__ bi,
                     float* __restrict__ out, int CI, int CO, int relu) {
    int i = blockIdx.x * 256 + threadIdx.x;
    if (i >= BB * CO) return;
    int b = i / CO, o = i % CO;
    const float* ir = in + (size_t)b * CI;
    const float* wr = w + (size_t)o * CI;
    float acc = 0.f;
    for (int c = 0; c < CI; ++c) acc += ir[c] * wr[c];
    if (sc) acc = acc * sc[o] + bi[o];
    else    acc += bi[o];
    if (relu) acc = fmaxf(acc, 0.f);
    out[i] = acc;
}

extern "C" void kernel_launch(void* const* d_in, const int* in_sizes, int n_in,
                              void* d_out, int out_size, void* d_ws, size_t ws_size,
                              hipStream_t stream) {
    const float* x    = (const float*)d_in[0];
    const float* w1   = (const float*)d_in[1];
    const float* s1   = (const float*)d_in[2];
    const float* b1   = (const float*)d_in[3];
    const float* w2   = (const float*)d_in[4];
    const float* s2   = (const float*)d_in[5];
    const float* b2   = (const float*)d_in[6];
    const float* w3   = (const float*)d_in[7];
    const float* s3   = (const float*)d_in[8];
    const float* b3   = (const float*)d_in[9];
    const float* w4   = (const float*)d_in[10];
    const float* s4   = (const float*)d_in[11];
    const float* b4   = (const float*)d_in[12];
    const float* w5   = (const float*)d_in[13];
    const float* s5   = (const float*)d_in[14];
    const float* b5   = (const float*)d_in[15];
    const float* fc1w = (const float*)d_in[16];
    const float* s6   = (const float*)d_in[17];
    const float* b6   = (const float*)d_in[18];
    const float* fc2w = (const float*)d_in[19];
    const float* s7   = (const float*)d_in[20];
    const float* b7   = (const float*)d_in[21];
    const float* fc3w = (const float*)d_in[22];
    const float* fc3b = (const float*)d_in[23];
    float* out = (float*)d_out;

    char* ws = (char*)d_ws;
    size_t off = 0;
    auto alloc = [&](size_t bytes) {
        void* p = ws + off;
        off = (off + bytes + 255) & ~(size_t)255;
        return p;
    };
    float* xt     = (float*)alloc((size_t)BB * NN * 3 * 4);
    float* xcat   = (float*)alloc((size_t)BB * NN * 512 * 4);
    int*   idx    = (int*)  alloc((size_t)BB * NN * KNN * 4);
    float* xx     = (float*)alloc((size_t)BB * NN * 4);
    float* wt1    = (float*)alloc(6 * 64 * 4);
    float* wt2    = (float*)alloc(128 * 64 * 4);
    float* wt3    = (float*)alloc(128 * 128 * 4);
    float* wt4    = (float*)alloc(256 * 256 * 4);
    float* w5t    = (float*)alloc(512 * 1024 * 4);
    float* pmax   = (float*)alloc((size_t)BB * 128 * 1024 * 4);
    float* psum   = (float*)alloc((size_t)BB * 128 * 1024 * 4);
    float* pooled = (float*)alloc((size_t)BB * 2048 * 4);
    float* f1     = (float*)alloc((size_t)BB * 512 * 4);
    float* f2     = (float*)alloc((size_t)BB * 256 * 4);

    k_transpose_x<<<(BB * NN * 3 + 255) / 256, 256, 0, stream>>>(x, xt);
    k_transpose_w<<<(64 * 6 + 255) / 256, 256, 0, stream>>>(w1, wt1, 64, 6);
    k_transpose_w<<<(64 * 128 + 255) / 256, 256, 0, stream>>>(w2, wt2, 64, 128);
    k_transpose_w<<<(128 * 128 + 255) / 256, 256, 0, stream>>>(w3, wt3, 128, 128);
    k_transpose_w<<<(256 * 256 + 255) / 256, 256, 0, stream>>>(w4, wt4, 256, 256);
    k_transpose_w<<<(1024 * 512 + 255) / 256, 256, 0, stream>>>(w5, w5t, 1024, 512);

    // EdgeConv 1: x (C=3) -> x1 (64) at xcat+0
    k_xx<3><<<(BB * NN + 255) / 256, 256, 0, stream>>>(xt, 3, xx);
    k_knn<3><<<BB * NN, 256, 0, stream>>>(xt, 3, xx, idx);
    k_edgeconv<3, 64, 16><<<BB * NN / 16, 256, 0, stream>>>(xt, 3, idx, wt1, s1, b1, xcat + 0, 512);

    // EdgeConv 2: x1 (64) -> x2 (64) at xcat+64
    k_xx<64><<<(BB * NN + 255) / 256, 256, 0, stream>>>(xcat + 0, 512, xx);
    k_knn<64><<<BB * NN, 256, 0, stream>>>(xcat + 0, 512, xx, idx);
    k_edgeconv<64, 64, 8><<<BB * NN / 8, 256, 0, stream>>>(xcat + 0, 512, idx, wt2, s2, b2, xcat + 64, 512);

    // EdgeConv 3: x2 (64) -> x3 (128) at xcat+128
    k_xx<64><<<(BB * NN + 255) / 256, 256, 0, stream>>>(xcat + 64, 512, xx);
    k_knn<64><<<BB * NN, 256, 0, stream>>>(xcat + 64, 512, xx, idx);
    k_edgeconv<64, 128, 8><<<BB * NN / 8, 256, 0, stream>>>(xcat + 64, 512, idx, wt3, s3, b3, xcat + 128, 512);

    // EdgeConv 4: x3 (128) -> x4 (256) at xcat+256
    k_xx<128><<<(BB * NN + 255) / 256, 256, 0, stream>>>(xcat + 128, 512, xx);
    k_knn<128><<<BB * NN, 256, 0, stream>>>(xcat + 128, 512, xx, idx);
    k_edgeconv<128, 256, 4><<<BB * NN / 4, 256, 0, stream>>>(xcat + 128, 512, idx, wt4, s4, b4, xcat + 256, 512);

    // conv5 + partial pooling
    k_conv5pool<<<BB * (NN / NT5), 256, 0, stream>>>(xcat, w5t, s5, b5, pmax, psum);
    k_poolreduce<<<(BB * 1024 + 255) / 256, 256, 0, stream>>>(pmax, psum, pooled);

    // FC head
    k_fc<<<(BB * 512 + 255) / 256, 256, 0, stream>>>(pooled, fc1w, s6, b6, f1, 2048, 512, 1);
    k_fc<<<(BB * 256 + 255) / 256, 256, 0, stream>>>(f1, fc2w, s7, b7, f2, 512, 256, 1);
    k_fc<<<(BB * 40 + 255) / 256, 256, 0, stream>>>(f2, fc3w, nullptr, fc3b, out, 256, 40, 0);
}

// Round 2
// 1790.275 us; speedup vs baseline: 3.7926x; 3.7926x over previous
//
#include <hip/hip_runtime.h>
#include <float.h>

#define BB 8
#define NN 2048
#define KNN 20

__device__ __forceinline__ float leaky(float h) { return h >= 0.f ? h : 0.2f * h; }

// ---------- transpose x (B,3,N) -> xt (B,N,3) ----------
__global__ void k_transpose_x(const float* __restrict__ x, float* __restrict__ xt) {
    int i = blockIdx.x * 256 + threadIdx.x;
    if (i >= BB * NN * 3) return;
    int c = i % 3; int n = (i / 3) % NN; int b = i / (3 * NN);
    xt[i] = x[((size_t)b * 3 + c) * NN + n];
}

// ---------- transpose w (CO,CI) -> wt (CI,CO) ----------
__global__ void k_transpose_w(const float* __restrict__ w, float* __restrict__ wt, int CO, int CI) {
    int i = blockIdx.x * 256 + threadIdx.x;
    if (i >= CO * CI) return;
    int o = i / CI, c = i % CI;
    wt[c * CO + o] = w[i];
}

// ---------- edgeconv weight split: w (CO, 2*CI) -> wtA (CI,CO) = w[:, :CI]^T,
// wtD (CI,CO) = (w[:, CI:] - w[:, :CI])^T ----------
__global__ void k_wpair(const float* __restrict__ w, float* __restrict__ wtA,
                        float* __restrict__ wtD, int CO, int CI) {
    int i = blockIdx.x * 256 + threadIdx.x;
    if (i >= CO * CI) return;
    int o = i / CI, c = i % CI;
    float a = w[(size_t)o * 2 * CI + c];
    float bb = w[(size_t)o * 2 * CI + CI + c];
    wtA[c * CO + o] = a;
    wtD[c * CO + o] = bb - a;
}

// ---------- squared norms per point ----------
template<int C>
__global__ void k_xx(const float* __restrict__ F, int FS, float* __restrict__ xx) {
    int i = blockIdx.x * 256 + threadIdx.x;
    if (i >= BB * NN) return;
    const float* r = F + (size_t)i * FS;
    float s = 0.f;
    #pragma unroll
    for (int c = 0; c < C; ++c) { float v = r[c]; s += v * v; }
    xx[i] = s;
}

// ---------- distance matrix tile kernel: D[bl][n][m] = 2*dot - xx[n] - xx[m] ----------
// grid: nb*1024 blocks (32x32 tiles of 64x64), 256 threads, 4x4 outputs/thread
template<int C>
__global__ __launch_bounds__(256) void k_dist(const float* __restrict__ F, int FS,
                                              const float* __restrict__ xx, int b0,
                                              float* __restrict__ D) {
    __shared__ float Xi[C * 64];
    __shared__ float Xj[C * 64];
    int tid = threadIdx.x;
    int bl = blockIdx.x >> 10;            // chunk-local batch
    int t  = blockIdx.x & 1023;
    int it = t >> 5, jt = t & 31;
    int i0 = it * 64, j0 = jt * 64;
    int b = b0 + bl;
    const float* Fb = F + (size_t)b * NN * FS;
    // stage: lanes walk consecutive rows -> conflict-free LDS writes
    if constexpr (C % 4 == 0) {
        for (int k = tid; k < 64 * (C / 4); k += 256) {
            int r = k & 63, cc = k >> 6;
            float vi[4], vj[4];
            *(float4*)vi = *(const float4*)(Fb + (size_t)(i0 + r) * FS + 4 * cc);
            *(float4*)vj = *(const float4*)(Fb + (size_t)(j0 + r) * FS + 4 * cc);
            #pragma unroll
            for (int u = 0; u < 4; ++u) {
                Xi[(4 * cc + u) * 64 + r] = vi[u];
                Xj[(4 * cc + u) * 64 + r] = vj[u];
            }
        }
    } else {
        for (int k = tid; k < 64 * C; k += 256) {
            int r = k & 63, c = k >> 6;
            Xi[c * 64 + r] = Fb[(size_t)(i0 + r) * FS + c];
            Xj[c * 64 + r] = Fb[(size_t)(j0 + r) * FS + c];
        }
    }
    __syncthreads();
    int ty = tid >> 4, tx = tid & 15;
    float acc[4][4] = {};
    for (int c = 0; c < C; ++c) {
        float a[4], bv[4];
        *(float4*)a  = *(const float4*)&Xi[c * 64 + 4 * ty];
        *(float4*)bv = *(const float4*)&Xj[c * 64 + 4 * tx];
        #pragma unroll
        for (int r = 0; r < 4; ++r)
            #pragma unroll
            for (int s = 0; s < 4; ++s) acc[r][s] += a[r] * bv[s];
    }
    const float* xxb = xx + (size_t)b * NN;
    float xxi[4], xxj[4];
    #pragma unroll
    for (int r = 0; r < 4; ++r) xxi[r] = xxb[i0 + 4 * ty + r];
    #pragma unroll
    for (int s = 0; s < 4; ++s) xxj[s] = xxb[j0 + 4 * tx + s];
    float* Dp = D + (size_t)bl * NN * NN;
    #pragma unroll
    for (int r = 0; r < 4; ++r) {
        float ov[4];
        #pragma unroll
        for (int s = 0; s < 4; ++s) ov[s] = 2.f * acc[r][s] - xxi[r] - xxj[s];
        *(float4*)(Dp + (size_t)(i0 + 4 * ty + r) * NN + j0 + 4 * tx) = *(float4*)ov;
    }
}

// ---------- top-20 selection: one wave per query, row in registers ----------
// grid: nb*512 blocks of 256 (4 waves)
__global__ __launch_bounds__(256) void k_select(const float* __restrict__ D,
                                                int* __restrict__ idxo, int b0) {
    int tid = threadIdx.x;
    int lane = tid & 63;
    int w = (blockIdx.x << 2) + (tid >> 6);   // chunk-local query id
    int bl = w / NN, n = w % NN;
    const float* row = D + (size_t)w * NN;
    float d[32];
    #pragma unroll
    for (int q = 0; q < 8; ++q)
        *(float4*)&d[4 * q] = *(const float4*)(row + 4 * lane + 256 * q);
    // per-lane running argmax
    float bv = d[0]; int bj = 0;
    #pragma unroll
    for (int j = 1; j < 32; ++j) if (d[j] > bv) { bv = d[j]; bj = j; }
    int* op = idxo + ((size_t)(b0 + bl) * NN + n) * KNN;
    for (int k = 0; k < KNN; ++k) {
        float rv = bv;
        int rm = 4 * lane + 256 * (bj >> 2) + (bj & 3);
        #pragma unroll
        for (int s = 1; s < 64; s <<= 1) {
            float ov = __shfl_xor(rv, s);
            int om = __shfl_xor(rm, s);
            if (ov > rv || (ov == rv && om < rm)) { rv = ov; rm = om; }
        }
        if (lane == 0) op[k] = rm;
        if (((rm >> 2) & 63) == lane) {   // owner lane clears + rescans
            int oj = ((rm >> 8) << 2) | (rm & 3);
            #pragma unroll
            for (int j = 0; j < 32; ++j) if (j == oj) d[j] = -FLT_MAX;
            bv = d[0]; bj = 0;
            #pragma unroll
            for (int j = 1; j < 32; ++j) if (d[j] > bv) { bv = d[j]; bj = j; }
        }
    }
}

// ---------- EdgeConv: wave<->points, lane<->OPL output channels ----------
// h[k][o] = dot(nbr_k, wA[:,o]) + dot(center, wD[:,o]); leaky(h*s+b); max over k
template<int CIN, int COUT, int OPL>
__global__ __launch_bounds__(256) void k_edgeconv(const float* __restrict__ F, int FS,
    const int* __restrict__ idx, const float* __restrict__ wtA, const float* __restrict__ wtD,
    const float* __restrict__ sc, const float* __restrict__ bi,
    float* __restrict__ out, int OS) {
    constexpr int LPP = COUT / OPL;   // lanes per point
    constexpr int PPW = 64 / LPP;     // points per wave
    constexpr int NPT = 4 * PPW;      // points per block (4 waves)
    __shared__ float ctr[NPT][CIN];
    __shared__ float nbr[NPT][KNN][CIN];
    int tid = threadIdx.x;
    int blk = blockIdx.x;
    int tilesPerB = NN / NPT;
    int b = blk / tilesPerB;
    int n0 = (blk % tilesPerB) * NPT;
    const float* Fb = F + (size_t)b * NN * FS;
    if constexpr (CIN % 4 == 0) {
        constexpr int CC = CIN / 4;
        for (int t = tid; t < NPT * CC; t += 256) {
            int p = t / CC, cc = t % CC;
            *(float4*)&ctr[p][4 * cc] = *(const float4*)(Fb + (size_t)(n0 + p) * FS + 4 * cc);
        }
        for (int t = tid; t < NPT * KNN * CC; t += 256) {
            int cc = t % CC; int k = (t / CC) % KNN; int p = t / (CC * KNN);
            int m = idx[((size_t)b * NN + n0 + p) * KNN + k];
            *(float4*)&nbr[p][k][4 * cc] = *(const float4*)(Fb + (size_t)m * FS + 4 * cc);
        }
    } else {
        for (int t = tid; t < NPT * CIN; t += 256) {
            int p = t / CIN, c = t % CIN;
            ctr[p][c] = Fb[(size_t)(n0 + p) * FS + c];
        }
        for (int t = tid; t < NPT * KNN * CIN; t += 256) {
            int c = t % CIN; int k = (t / CIN) % KNN; int p = t / (CIN * KNN);
            int m = idx[((size_t)b * NN + n0 + p) * KNN + k];
            nbr[p][k][c] = Fb[(size_t)m * FS + c];
        }
    }
    __syncthreads();
    int lane = tid & 63, wave = tid >> 6;
    int sub = lane / LPP;
    int p = wave * PPW + sub;
    int o0 = OPL * (lane % LPP);
    // center term
    float ct[OPL];
    #pragma unroll
    for (int u = 0; u < OPL; ++u) ct[u] = 0.f;
    if constexpr (CIN % 4 == 0) {
        for (int cc = 0; cc < CIN / 4; ++cc) {
            float cv[4];
            *(float4*)cv = *(const float4*)&ctr[p][4 * cc];
            #pragma unroll
            for (int cu = 0; cu < 4; ++cu) {
                const float* wd = wtD + (size_t)(4 * cc + cu) * COUT + o0;
                #pragma unroll
                for (int u = 0; u < OPL; ++u) ct[u] += cv[cu] * wd[u];
            }
        }
    } else {
        for (int c = 0; c < CIN; ++c) {
            float cv = ctr[p][c];
            const float* wd = wtD + (size_t)c * COUT + o0;
            #pragma unroll
            for (int u = 0; u < OPL; ++u) ct[u] += cv * wd[u];
        }
    }
    float acc[KNN][OPL];
    #pragma unroll
    for (int k = 0; k < KNN; ++k)
        #pragma unroll
        for (int u = 0; u < OPL; ++u) acc[k][u] = ct[u];
    // neighbor term
    if constexpr (CIN % 4 == 0) {
        for (int cc = 0; cc < CIN / 4; ++cc) {
            float wa[4][OPL];
            #pragma unroll
            for (int cu = 0; cu < 4; ++cu) {
                const float* ws_ = wtA + (size_t)(4 * cc + cu) * COUT + o0;
                #pragma unroll
                for (int u = 0; u < OPL; ++u) wa[cu][u] = ws_[u];
            }
            #pragma unroll
            for (int k = 0; k < KNN; ++k) {
                float nv[4];
                *(float4*)nv = *(const float4*)&nbr[p][k][4 * cc];
                #pragma unroll
                for (int cu = 0; cu < 4; ++cu)
                    #pragma unroll
                    for (int u = 0; u < OPL; ++u) acc[k][u] += nv[cu] * wa[cu][u];
            }
        }
    } else {
        for (int c = 0; c < CIN; ++c) {
            float wa[OPL];
            const float* ws_ = wtA + (size_t)c * COUT + o0;
            #pragma unroll
            for (int u = 0; u < OPL; ++u) wa[u] = ws_[u];
            #pragma unroll
            for (int k = 0; k < KNN; ++k) {
                float nv = nbr[p][k][c];
                #pragma unroll
                for (int u = 0; u < OPL; ++u) acc[k][u] += nv * wa[u];
            }
        }
    }
    // epilogue: scale/bias/leaky + max over k
    float mx[OPL];
    #pragma unroll
    for (int u = 0; u < OPL; ++u) mx[u] = -FLT_MAX;
    #pragma unroll
    for (int k = 0; k < KNN; ++k)
        #pragma unroll
        for (int u = 0; u < OPL; ++u) {
            float h = leaky(acc[k][u] * sc[o0 + u] + bi[o0 + u]);
            mx[u] = fmaxf(mx[u], h);
        }
    float* op = out + ((size_t)b * NN + n0 + p) * OS + o0;
    if constexpr (OPL == 4) { *(float4*)op = *(float4*)mx; }
    else if constexpr (OPL == 2) { *(float2*)op = *(float2*)mx; }
    else {
        #pragma unroll
        for (int u = 0; u < OPL; ++u) op[u] = mx[u];
    }
}

// ---------- conv5 (512 -> 1024) fused with partial max/mean pooling ----------
#define NT5 16
__global__ void k_conv5pool(const float* __restrict__ xcat,
                            const float* __restrict__ w5t,  // (512,1024)
                            const float* __restrict__ s5, const float* __restrict__ b5,
                            float* __restrict__ pmax, float* __restrict__ psum) {
    __shared__ float xr[NT5 * 512];
    int blk = blockIdx.x;
    int chunks = NN / NT5;            // 128
    int b = blk / chunks;
    int ch = blk % chunks;
    int n0 = ch * NT5;
    int tid = threadIdx.x;
    const float* base = xcat + ((size_t)b * NN + n0) * 512;
    for (int i = tid; i < NT5 * 512; i += 256) xr[i] = base[i];
    __syncthreads();
    float acc[NT5][4];
    #pragma unroll
    for (int p = 0; p < NT5; ++p)
        #pragma unroll
        for (int j = 0; j < 4; ++j) acc[p][j] = 0.f;
    for (int c = 0; c < 512; ++c) {
        float w0 = w5t[(size_t)c * 1024 + tid];
        float w1 = w5t[(size_t)c * 1024 + tid + 256];
        float w2 = w5t[(size_t)c * 1024 + tid + 512];
        float w3 = w5t[(size_t)c * 1024 + tid + 768];
        #pragma unroll
        for (int p = 0; p < NT5; ++p) {
            float xv = xr[p * 512 + c];
            acc[p][0] += xv * w0; acc[p][1] += xv * w1;
            acc[p][2] += xv * w2; acc[p][3] += xv * w3;
        }
    }
    #pragma unroll
    for (int j = 0; j < 4; ++j) {
        int o = tid + 256 * j;
        float sv = s5[o], bv = b5[o];
        float mx = -FLT_MAX, sm = 0.f;
        #pragma unroll
        for (int p = 0; p < NT5; ++p) {
            float h = leaky(acc[p][j] * sv + bv);
            mx = fmaxf(mx, h); sm += h;
        }
        pmax[((size_t)b * chunks + ch) * 1024 + o] = mx;
        psum[((size_t)b * chunks + ch) * 1024 + o] = sm;
    }
}

__global__ void k_poolreduce(const float* __restrict__ pmax, const float* __restrict__ psum,
                             float* __restrict__ pooled) {
    int i = blockIdx.x * 256 + threadIdx.x;   // b*1024 + o
    if (i >= BB * 1024) return;
    int b = i / 1024, o = i % 1024;
    int chunks = NN / NT5;
    float mx = -FLT_MAX, sm = 0.f;
    for (int ch = 0; ch < chunks; ++ch) {
        mx = fmaxf(mx, pmax[((size_t)b * chunks + ch) * 1024 + o]);
        sm += psum[((size_t)b * chunks + ch) * 1024 + o];
    }
    pooled[(size_t)b * 2048 + o] = mx;
    pooled[(size_t)b * 2048 + 1024 + o] = sm / (float)NN;
}

// ---------- FC ----------
__global__ void k_fc(const float* __restrict__ in, const float* __restrict__ w,
                     const float* __restrict__ sc, const float* __restrict__ bi,
                     float* __restrict__ out, int CI, int CO, int relu) {
    int i = blockIdx.x * 256 + threadIdx.x;
    if (i >= BB * CO) return;
    int b = i / CO, o = i % CO;
    const float* ir = in + (size_t)b * CI;
    const float* wr = w + (size_t)o * CI;
    float acc = 0.f;
    for (int c = 0; c < CI; ++c) acc += ir[c] * wr[c];
    if (sc) acc = acc * sc[o] + bi[o];
    else    acc += bi[o];
    if (relu) acc = fmaxf(acc, 0.f);
    out[i] = acc;
}

extern "C" void kernel_launch(void* const* d_in, const int* in_sizes, int n_in,
                              void* d_out, int out_size, void* d_ws, size_t ws_size,
                              hipStream_t stream) {
    const float* x    = (const float*)d_in[0];
    const float* w1   = (const float*)d_in[1];
    const float* s1   = (const float*)d_in[2];
    const float* b1   = (const float*)d_in[3];
    const float* w2   = (const float*)d_in[4];
    const float* s2   = (const float*)d_in[5];
    const float* b2   = (const float*)d_in[6];
    const float* w3   = (const float*)d_in[7];
    const float* s3   = (const float*)d_in[8];
    const float* b3   = (const float*)d_in[9];
    const float* w4   = (const float*)d_in[10];
    const float* s4   = (const float*)d_in[11];
    const float* b4   = (const float*)d_in[12];
    const float* w5   = (const float*)d_in[13];
    const float* s5   = (const float*)d_in[14];
    const float* b5   = (const float*)d_in[15];
    const float* fc1w = (const float*)d_in[16];
    const float* s6   = (const float*)d_in[17];
    const float* b6   = (const float*)d_in[18];
    const float* fc2w = (const float*)d_in[19];
    const float* s7   = (const float*)d_in[20];
    const float* b7   = (const float*)d_in[21];
    const float* fc3w = (const float*)d_in[22];
    const float* fc3b = (const float*)d_in[23];
    float* out = (float*)d_out;

    char* ws = (char*)d_ws;
    size_t off = 0;
    auto alloc = [&](size_t bytes) {
        void* p = ws + off;
        off = (off + bytes + 255) & ~(size_t)255;
        return p;
    };
    float* xt   = (float*)alloc((size_t)BB * NN * 3 * 4);
    float* xcat = (float*)alloc((size_t)BB * NN * 512 * 4);
    int*   idx  = (int*)  alloc((size_t)BB * NN * KNN * 4);
    float* xx   = (float*)alloc((size_t)BB * NN * 4);
    float* wtA1 = (float*)alloc(3 * 64 * 4);
    float* wtD1 = (float*)alloc(3 * 64 * 4);
    float* wtA2 = (float*)alloc(64 * 64 * 4);
    float* wtD2 = (float*)alloc(64 * 64 * 4);
    float* wtA3 = (float*)alloc(64 * 128 * 4);
    float* wtD3 = (float*)alloc(64 * 128 * 4);
    float* wtA4 = (float*)alloc(128 * 256 * 4);
    float* wtD4 = (float*)alloc(128 * 256 * 4);
    size_t base_end = off;

    // UNION region: D (KNN phase) overlaps w5t/pmax/psum/pooled/f1/f2 (head phase)
    const size_t D1 = (size_t)NN * NN * 4;   // 16.78 MB per batch
    size_t avail = ws_size > base_end ? ws_size - base_end : 0;
    int nbD = (int)(avail / D1);
    if (nbD < 1) nbD = 1;
    if (nbD > BB) nbD = BB;
    float* D      = (float*)(ws + base_end);
    float* w5t    = (float*)(ws + base_end);
    float* pmax   = w5t + 512 * 1024;
    float* psum   = pmax + (size_t)BB * 128 * 1024;
    float* pooled = psum + (size_t)BB * 128 * 1024;
    float* f1     = pooled + (size_t)BB * 2048;
    float* f2     = f1 + (size_t)BB * 512;

    // weight prep (edgeconv weights only; w5 transposed later into union region)
    k_transpose_x<<<(BB * NN * 3 + 255) / 256, 256, 0, stream>>>(x, xt);
    k_wpair<<<(64 * 3 + 255) / 256, 256, 0, stream>>>(w1, wtA1, wtD1, 64, 3);
    k_wpair<<<(64 * 64 + 255) / 256, 256, 0, stream>>>(w2, wtA2, wtD2, 64, 64);
    k_wpair<<<(128 * 64 + 255) / 256, 256, 0, stream>>>(w3, wtA3, wtD3, 128, 64);
    k_wpair<<<(256 * 128 + 255) / 256, 256, 0, stream>>>(w4, wtA4, wtD4, 256, 128);

    auto knn = [&](auto cTag, const float* F, int FS) {
        constexpr int C = decltype(cTag)::value;
        k_xx<C><<<(BB * NN + 255) / 256, 256, 0, stream>>>(F, FS, xx);
        for (int b0 = 0; b0 < BB; b0 += nbD) {
            int nb = BB - b0 < nbD ? BB - b0 : nbD;
            k_dist<C><<<nb * 1024, 256, 0, stream>>>(F, FS, xx, b0, D);
            k_select<<<nb * 512, 256, 0, stream>>>(D, idx, b0);
        }
    };

    // EdgeConv 1: xt (C=3) -> x1 (64) at xcat+0
    knn(std::integral_constant<int, 3>{}, xt, 3);
    k_edgeconv<3, 64, 4><<<BB * NN / 16, 256, 0, stream>>>(xt, 3, idx, wtA1, wtD1, s1, b1, xcat + 0, 512);

    // EdgeConv 2: x1 (64) -> x2 (64) at xcat+64
    knn(std::integral_constant<int, 64>{}, xcat + 0, 512);
    k_edgeconv<64, 64, 2><<<BB * NN / 8, 256, 0, stream>>>(xcat + 0, 512, idx, wtA2, wtD2, s2, b2, xcat + 64, 512);

    // EdgeConv 3: x2 (64) -> x3 (128) at xcat+128
    knn(std::integral_constant<int, 64>{}, xcat + 64, 512);
    k_edgeconv<64, 128, 4><<<BB * NN / 8, 256, 0, stream>>>(xcat + 64, 512, idx, wtA3, wtD3, s3, b3, xcat + 128, 512);

    // EdgeConv 4: x3 (128) -> x4 (256) at xcat+256
    knn(std::integral_constant<int, 128>{}, xcat + 128, 512);
    k_edgeconv<128, 256, 4><<<BB * NN / 4, 256, 0, stream>>>(xcat + 128, 512, idx, wtA4, wtD4, s4, b4, xcat + 256, 512);

    // head (D is dead now; union region reused)
    k_transpose_w<<<(1024 * 512 + 255) / 256, 256, 0, stream>>>(w5, w5t, 1024, 512);
    k_conv5pool<<<BB * (NN / NT5), 256, 0, stream>>>(xcat, w5t, s5, b5, pmax, psum);
    k_poolreduce<<<(BB * 1024 + 255) / 256, 256, 0, stream>>>(pmax, psum, pooled);
    k_fc<<<(BB * 512 + 255) / 256, 256, 0, stream>>>(pooled, fc1w, s6, b6, f1, 2048, 512, 1);
    k_fc<<<(BB * 256 + 255) / 256, 256, 0, stream>>>(f1, fc2w, s7, b7, f2, 512, 256, 1);
    k_fc<<<(BB * 40 + 255) / 256, 256, 0, stream>>>(f2, fc3w, nullptr, fc3b, out, 256, 40, 0);
}

// Round 3
// 1481.847 us; speedup vs baseline: 4.5820x; 1.2081x over previous
//
#include <hip/hip_runtime.h>
#include <float.h>
#include <type_traits>

#define BB 8
#define NN 2048
#define KNN 20

__device__ __forceinline__ float leaky(float v) { return fmaxf(v, 0.2f * v); }

// ---------- transpose x (B,3,N) -> xt (B,N,3) ----------
__global__ void k_transpose_x(const float* __restrict__ x, float* __restrict__ xt) {
    int i = blockIdx.x * 256 + threadIdx.x;
    if (i >= BB * NN * 3) return;
    int c = i % 3; int n = (i / 3) % NN; int b = i / (3 * NN);
    xt[i] = x[((size_t)b * 3 + c) * NN + n];
}

// ---------- transpose w (CO,CI) -> wt (CI,CO) ----------
__global__ void k_transpose_w(const float* __restrict__ w, float* __restrict__ wt, int CO, int CI) {
    int i = blockIdx.x * 256 + threadIdx.x;
    if (i >= CO * CI) return;
    int o = i / CI, c = i % CI;
    wt[c * CO + o] = w[i];
}

// ---------- edgeconv weight split: w (CO, 2*CI) -> wtA (CI,CO), wtD (CI,CO) ----------
__global__ void k_wpair(const float* __restrict__ w, float* __restrict__ wtA,
                        float* __restrict__ wtD, int CO, int CI) {
    int i = blockIdx.x * 256 + threadIdx.x;
    if (i >= CO * CI) return;
    int o = i / CI, c = i % CI;
    float a = w[(size_t)o * 2 * CI + c];
    float bb = w[(size_t)o * 2 * CI + CI + c];
    wtA[c * CO + o] = a;
    wtD[c * CO + o] = bb - a;
}

// ---------- squared norms per point ----------
template<int C>
__global__ void k_xx(const float* __restrict__ F, int FS, float* __restrict__ xx) {
    int i = blockIdx.x * 256 + threadIdx.x;
    if (i >= BB * NN) return;
    const float* r = F + (size_t)i * FS;
    float s = 0.f;
    #pragma unroll
    for (int c = 0; c < C; ++c) { float v = r[c]; s += v * v; }
    xx[i] = s;
}

// ---------- distance matrix: D[bl][n][m] = 2*dot - xx[n] - xx[m]; c-chunked LDS ----------
template<int C>
__global__ __launch_bounds__(256) void k_dist(const float* __restrict__ F, int FS,
                                              const float* __restrict__ xx, int b0,
                                              float* __restrict__ D) {
    constexpr int CCH = (C >= 32) ? 32 : C;
    constexpr int NCH = C / CCH;
    __shared__ __align__(16) float Xi[CCH * 64];
    __shared__ __align__(16) float Xj[CCH * 64];
    int tid = threadIdx.x;
    int bl = blockIdx.x >> 10;
    int t  = blockIdx.x & 1023;
    int i0 = (t >> 5) * 64, j0 = (t & 31) * 64;
    int b = b0 + bl;
    const float* Fb = F + (size_t)b * NN * FS;
    int ty = tid >> 4, tx = tid & 15;
    float acc[4][4] = {};
    for (int ch = 0; ch < NCH; ++ch) {
        int cb = ch * CCH;
        if (ch) __syncthreads();
        if constexpr (CCH % 4 == 0) {
            for (int k = tid; k < 64 * (CCH / 4); k += 256) {
                int r = k & 63, cc = k >> 6;
                float vi[4], vj[4];
                *(float4*)vi = *(const float4*)(Fb + (size_t)(i0 + r) * FS + cb + 4 * cc);
                *(float4*)vj = *(const float4*)(Fb + (size_t)(j0 + r) * FS + cb + 4 * cc);
                #pragma unroll
                for (int u = 0; u < 4; ++u) {
                    Xi[(4 * cc + u) * 64 + r] = vi[u];
                    Xj[(4 * cc + u) * 64 + r] = vj[u];
                }
            }
        } else {
            for (int k = tid; k < 64 * CCH; k += 256) {
                int r = k & 63, c = k >> 6;
                Xi[c * 64 + r] = Fb[(size_t)(i0 + r) * FS + cb + c];
                Xj[c * 64 + r] = Fb[(size_t)(j0 + r) * FS + cb + c];
            }
        }
        __syncthreads();
        for (int c = 0; c < CCH; ++c) {
            float a[4], bv[4];
            *(float4*)a  = *(const float4*)&Xi[c * 64 + 4 * ty];
            *(float4*)bv = *(const float4*)&Xj[c * 64 + 4 * tx];
            #pragma unroll
            for (int r = 0; r < 4; ++r)
                #pragma unroll
                for (int s = 0; s < 4; ++s) acc[r][s] += a[r] * bv[s];
        }
    }
    const float* xxb = xx + (size_t)b * NN;
    float xxi[4], xxj[4];
    #pragma unroll
    for (int r = 0; r < 4; ++r) xxi[r] = xxb[i0 + 4 * ty + r];
    #pragma unroll
    for (int s = 0; s < 4; ++s) xxj[s] = xxb[j0 + 4 * tx + s];
    float* Dp = D + (size_t)bl * NN * NN;
    #pragma unroll
    for (int r = 0; r < 4; ++r) {
        float ov[4];
        #pragma unroll
        for (int s = 0; s < 4; ++s) ov[s] = 2.f * acc[r][s] - xxi[r] - xxj[s];
        *(float4*)(Dp + (size_t)(i0 + 4 * ty + r) * NN + j0 + 4 * tx) = *(float4*)ov;
    }
}

// ---------- top-20 selection: one wave per query, row in registers ----------
__global__ __launch_bounds__(256) void k_select(const float* __restrict__ D,
                                                int* __restrict__ idxo, int b0) {
    int tid = threadIdx.x;
    int lane = tid & 63;
    int w = (blockIdx.x << 2) + (tid >> 6);
    int bl = w / NN, n = w % NN;
    const float* row = D + (size_t)w * NN;
    float d[32];
    #pragma unroll
    for (int q = 0; q < 8; ++q)
        *(float4*)&d[4 * q] = *(const float4*)(row + 4 * lane + 256 * q);
    float bv = d[0]; int bj = 0;
    #pragma unroll
    for (int j = 1; j < 32; ++j) if (d[j] > bv) { bv = d[j]; bj = j; }
    int* op = idxo + ((size_t)(b0 + bl) * NN + n) * KNN;
    for (int k = 0; k < KNN; ++k) {
        float rv = bv;
        int rm = 4 * lane + 256 * (bj >> 2) + (bj & 3);
        #pragma unroll
        for (int s = 1; s < 64; s <<= 1) {
            float ov = __shfl_xor(rv, s);
            int om = __shfl_xor(rm, s);
            if (ov > rv || (ov == rv && om < rm)) { rv = ov; rm = om; }
        }
        if (lane == 0) op[k] = rm;
        if (((rm >> 2) & 63) == lane) {
            int oj = ((rm >> 8) << 2) | (rm & 3);
            #pragma unroll
            for (int j = 0; j < 32; ++j) if (j == oj) d[j] = -FLT_MAX;
            bv = d[0]; bj = 0;
            #pragma unroll
            for (int j = 1; j < 32; ++j) if (d[j] > bv) { bv = d[j]; bj = j; }
        }
    }
}

// ---------- pair GEMM: Y = F*wtA, C2 = F*wtD  (64 rows x 64 cols per block) ----------
template<int CIN, int COUT>
__global__ __launch_bounds__(256) void k_gemm_pair(const float* __restrict__ F, int FS, int b0,
    const float* __restrict__ wtA, const float* __restrict__ wtD,
    float* __restrict__ Y, float* __restrict__ C2) {
    constexpr int CCH = (CIN >= 32) ? 32 : CIN;
    constexpr int NCH = CIN / CCH;
    __shared__ __align__(16) float Xi[CCH * 64];
    __shared__ __align__(16) float Wa[CCH * 64];
    __shared__ __align__(16) float Wd[CCH * 64];
    int tid = threadIdx.x;
    int r0 = blockIdx.x * 64;            // chunk-local row base (bl*NN + n0)
    int c0 = blockIdx.y * 64;
    int b = b0 + r0 / NN;
    int n0 = r0 % NN;
    const float* Fb = F + ((size_t)b * NN + n0) * FS;
    int ty = tid >> 4, tx = tid & 15;
    float accY[4][4] = {}, accD[4][4] = {};
    for (int ch = 0; ch < NCH; ++ch) {
        int cb = ch * CCH;
        if (ch) __syncthreads();
        if constexpr (CCH % 4 == 0) {
            for (int t = tid; t < 64 * (CCH / 4); t += 256) {
                int r = t & 63, cc = t >> 6;
                float v[4];
                *(float4*)v = *(const float4*)(Fb + (size_t)r * FS + cb + 4 * cc);
                #pragma unroll
                for (int u = 0; u < 4; ++u) Xi[(4 * cc + u) * 64 + r] = v[u];
            }
            for (int t = tid; t < CCH * 16; t += 256) {
                int c = t >> 4, q = t & 15;
                *(float4*)&Wa[c * 64 + 4 * q] = *(const float4*)(wtA + (size_t)(cb + c) * COUT + c0 + 4 * q);
                *(float4*)&Wd[c * 64 + 4 * q] = *(const float4*)(wtD + (size_t)(cb + c) * COUT + c0 + 4 * q);
            }
        } else {
            for (int t = tid; t < 64 * CCH; t += 256) {
                int r = t & 63, c = t >> 6;
                Xi[c * 64 + r] = Fb[(size_t)r * FS + cb + c];
            }
            for (int t = tid; t < CCH * 64; t += 256) {
                int col = t & 63, c = t >> 6;
                Wa[c * 64 + col] = wtA[(size_t)(cb + c) * COUT + c0 + col];
                Wd[c * 64 + col] = wtD[(size_t)(cb + c) * COUT + c0 + col];
            }
        }
        __syncthreads();
        for (int c = 0; c < CCH; ++c) {
            float a[4], wa[4], wd[4];
            *(float4*)a  = *(const float4*)&Xi[c * 64 + 4 * ty];
            *(float4*)wa = *(const float4*)&Wa[c * 64 + 4 * tx];
            *(float4*)wd = *(const float4*)&Wd[c * 64 + 4 * tx];
            #pragma unroll
            for (int r = 0; r < 4; ++r)
                #pragma unroll
                for (int s = 0; s < 4; ++s) {
                    accY[r][s] += a[r] * wa[s];
                    accD[r][s] += a[r] * wd[s];
                }
        }
    }
    #pragma unroll
    for (int r = 0; r < 4; ++r) {
        size_t ro = (size_t)(r0 + 4 * ty + r) * COUT + c0 + 4 * tx;
        *(float4*)(Y  + ro) = *(float4*)accY[r];
        *(float4*)(C2 + ro) = *(float4*)accD[r];
    }
}

// ---------- gather-max: out[p][o] = max_k leaky((Y[idx[p][k]][o] + C2[p][o])*s + b) ----------
template<int COUT>
__global__ __launch_bounds__(256) void k_gather(const float* __restrict__ Y,
    const float* __restrict__ C2, const int* __restrict__ idx,
    const float* __restrict__ sc, const float* __restrict__ bi,
    float* __restrict__ out, int OS, int b0) {
    constexpr int LPP = COUT / 4;
    constexpr int PPW = 64 / LPP;
    constexpr int PPB = 4 * PPW;
    int tid = threadIdx.x;
    int lane = tid & 63, wv = tid >> 6;
    int pl = blockIdx.x * PPB + wv * PPW + lane / LPP;   // chunk-local point
    int bl = pl / NN, n = pl % NN;
    int o0 = 4 * (lane % LPP);
    float c2[4], s4[4], b4[4];
    *(float4*)c2 = *(const float4*)(C2 + (size_t)pl * COUT + o0);
    *(float4*)s4 = *(const float4*)(sc + o0);
    *(float4*)b4 = *(const float4*)(bi + o0);
    const int* ip = idx + ((size_t)(b0 + bl) * NN + n) * KNN;
    const float* Yb = Y + (size_t)bl * NN * COUT;
    float mx[4] = {-FLT_MAX, -FLT_MAX, -FLT_MAX, -FLT_MAX};
    for (int k = 0; k < KNN; ++k) {
        int m = ip[k];
        float y[4];
        *(float4*)y = *(const float4*)(Yb + (size_t)m * COUT + o0);
        #pragma unroll
        for (int u = 0; u < 4; ++u) {
            float v = (y[u] + c2[u]) * s4[u] + b4[u];
            mx[u] = fmaxf(mx[u], leaky(v));
        }
    }
    float* op = out + ((size_t)(b0 + bl) * NN + n) * OS + o0;
    *(float4*)op = *(float4*)mx;
}

// ---------- conv5: 16384x1024x512 GEMM, 64x128 tile, fused partial max/sum pooling ----------
__global__ __launch_bounds__(256) void k_conv5(const float* __restrict__ xcat,
    const float* __restrict__ w5t, const float* __restrict__ s5, const float* __restrict__ b5,
    float* __restrict__ pmax, float* __restrict__ psum) {
    __shared__ __align__(16) float Xi[32 * 64];    // 8KB  [c][row]
    __shared__ __align__(16) float Wj[32 * 128];   // 16KB [c][col]
    int tid = threadIdx.x;
    int ty = tid >> 4, tx = tid & 15;
    int r0 = blockIdx.x * 64;
    int col0 = blockIdx.y * 128;
    int b = r0 / NN, tileInB = (r0 % NN) / 64;
    const float* Fb = xcat + (size_t)r0 * 512;
    float acc[4][8] = {};
    for (int ch = 0; ch < 16; ++ch) {
        int cb = ch * 32;
        if (ch) __syncthreads();
        for (int t = tid; t < 64 * 8; t += 256) {
            int r = t & 63, cc = t >> 6;
            float v[4];
            *(float4*)v = *(const float4*)(Fb + (size_t)r * 512 + cb + 4 * cc);
            #pragma unroll
            for (int u = 0; u < 4; ++u) Xi[(4 * cc + u) * 64 + r] = v[u];
        }
        for (int t = tid; t < 32 * 32; t += 256) {
            int c = t >> 5, q = t & 31;
            *(float4*)&Wj[c * 128 + 4 * q] = *(const float4*)(w5t + (size_t)(cb + c) * 1024 + col0 + 4 * q);
        }
        __syncthreads();
        for (int c = 0; c < 32; ++c) {
            float a[4], w[8];
            *(float4*)a      = *(const float4*)&Xi[c * 64 + 4 * ty];
            *(float4*)w      = *(const float4*)&Wj[c * 128 + 8 * tx];
            *(float4*)(w + 4) = *(const float4*)&Wj[c * 128 + 8 * tx + 4];
            #pragma unroll
            for (int r = 0; r < 4; ++r)
                #pragma unroll
                for (int u = 0; u < 8; ++u) acc[r][u] += a[r] * w[u];
        }
    }
    // epilogue: scale/bias/leaky + per-thread partial pool over 4 rows
    float hmx[8], hsm[8];
    #pragma unroll
    for (int u = 0; u < 8; ++u) { hmx[u] = -FLT_MAX; hsm[u] = 0.f; }
    #pragma unroll
    for (int u = 0; u < 8; ++u) {
        int o = col0 + 8 * tx + u;
        float sv = s5[o], bv = b5[o];
        #pragma unroll
        for (int r = 0; r < 4; ++r) {
            float h = leaky(acc[r][u] * sv + bv);
            hmx[u] = fmaxf(hmx[u], h);
            hsm[u] += h;
        }
    }
    __syncthreads();
    float* redM = Xi;          // 16*128 = 2048 floats
    float* redS = Wj;
    #pragma unroll
    for (int u = 0; u < 8; ++u) {
        redM[ty * 128 + 8 * tx + u] = hmx[u];
        redS[ty * 128 + 8 * tx + u] = hsm[u];
    }
    __syncthreads();
    for (int s = 8; s > 0; s >>= 1) {
        if (ty < s) {
            #pragma unroll
            for (int u = 0; u < 8; ++u) {
                int c = 8 * tx + u;
                redM[ty * 128 + c] = fmaxf(redM[ty * 128 + c], redM[(ty + s) * 128 + c]);
                redS[ty * 128 + c] += redS[(ty + s) * 128 + c];
            }
        }
        __syncthreads();
    }
    if (ty == 0) {
        #pragma unroll
        for (int u = 0; u < 8; ++u) {
            int c = 8 * tx + u;
            size_t o = ((size_t)b * 32 + tileInB) * 1024 + col0 + c;
            pmax[o] = redM[c];
            psum[o] = redS[c];
        }
    }
}

__global__ void k_poolreduce(const float* __restrict__ pmax, const float* __restrict__ psum,
                             float* __restrict__ pooled) {
    int i = blockIdx.x * 256 + threadIdx.x;
    if (i >= BB * 1024) return;
    int b = i / 1024, o = i % 1024;
    float mx = -FLT_MAX, sm = 0.f;
    for (int ch = 0; ch < 32; ++ch) {
        mx = fmaxf(mx, pmax[((size_t)b * 32 + ch) * 1024 + o]);
        sm += psum[((size_t)b * 32 + ch) * 1024 + o];
    }
    pooled[(size_t)b * 2048 + o] = mx;
    pooled[(size_t)b * 2048 + 1024 + o] = sm / (float)NN;
}

// ---------- FC ----------
__global__ void k_fc(const float* __restrict__ in, const float* __restrict__ w,
                     const float* __restrict__ sc, const float* __restrict__ bi,
                     float* __restrict__ out, int CI, int CO, int relu) {
    int i = blockIdx.x * 256 + threadIdx.x;
    if (i >= BB * CO) return;
    int b = i / CO, o = i % CO;
    const float* ir = in + (size_t)b * CI;
    const float* wr = w + (size_t)o * CI;
    float acc = 0.f;
    for (int c = 0; c < CI; ++c) acc += ir[c] * wr[c];
    if (sc) acc = acc * sc[o] + bi[o];
    else    acc += bi[o];
    if (relu) acc = fmaxf(acc, 0.f);
    out[i] = acc;
}

extern "C" void kernel_launch(void* const* d_in, const int* in_sizes, int n_in,
                              void* d_out, int out_size, void* d_ws, size_t ws_size,
                              hipStream_t stream) {
    const float* x    = (const float*)d_in[0];
    const float* w1   = (const float*)d_in[1];
    const float* s1   = (const float*)d_in[2];
    const float* b1   = (const float*)d_in[3];
    const float* w2   = (const float*)d_in[4];
    const float* s2   = (const float*)d_in[5];
    const float* b2   = (const float*)d_in[6];
    const float* w3   = (const float*)d_in[7];
    const float* s3   = (const float*)d_in[8];
    const float* b3   = (const float*)d_in[9];
    const float* w4   = (const float*)d_in[10];
    const float* s4   = (const float*)d_in[11];
    const float* b4   = (const float*)d_in[12];
    const float* w5   = (const float*)d_in[13];
    const float* s5   = (const float*)d_in[14];
    const float* b5   = (const float*)d_in[15];
    const float* fc1w = (const float*)d_in[16];
    const float* s6   = (const float*)d_in[17];
    const float* b6   = (const float*)d_in[18];
    const float* fc2w = (const float*)d_in[19];
    const float* s7   = (const float*)d_in[20];
    const float* b7   = (const float*)d_in[21];
    const float* fc3w = (const float*)d_in[22];
    const float* fc3b = (const float*)d_in[23];
    float* out = (float*)d_out;

    char* ws = (char*)d_ws;
    size_t off = 0;
    auto alloc = [&](size_t bytes) {
        void* p = ws + off;
        off = (off + bytes + 255) & ~(size_t)255;
        return p;
    };
    float* xt   = (float*)alloc((size_t)BB * NN * 3 * 4);
    float* xcat = (float*)alloc((size_t)BB * NN * 512 * 4);
    int*   idx  = (int*)  alloc((size_t)BB * NN * KNN * 4);
    float* xx   = (float*)alloc((size_t)BB * NN * 4);
    float* wtA1 = (float*)alloc(3 * 64 * 4);
    float* wtD1 = (float*)alloc(3 * 64 * 4);
    float* wtA2 = (float*)alloc(64 * 64 * 4);
    float* wtD2 = (float*)alloc(64 * 64 * 4);
    float* wtA3 = (float*)alloc(64 * 128 * 4);
    float* wtD3 = (float*)alloc(64 * 128 * 4);
    float* wtA4 = (float*)alloc(128 * 256 * 4);
    float* wtD4 = (float*)alloc(128 * 256 * 4);
    size_t base_end = off;

    // UNION region: D (dist phase) / Y+C2 (transform phase) / head buffers
    const size_t D1 = (size_t)NN * NN * 4;
    size_t avail = ws_size > base_end ? ws_size - base_end : 0;
    int nbD = (int)(avail / D1);
    if (nbD < 1) nbD = 1;
    if (nbD > BB) nbD = BB;
    char* uni = ws + base_end;
    float* D      = (float*)uni;
    float* w5t    = (float*)uni;
    float* pmax   = w5t + 512 * 1024;
    float* psum   = pmax + (size_t)BB * 32 * 1024;
    float* pooled = psum + (size_t)BB * 32 * 1024;
    float* f1     = pooled + (size_t)BB * 2048;
    float* f2     = f1 + (size_t)BB * 512;

    k_transpose_x<<<(BB * NN * 3 + 255) / 256, 256, 0, stream>>>(x, xt);
    k_wpair<<<(64 * 3 + 255) / 256, 256, 0, stream>>>(w1, wtA1, wtD1, 64, 3);
    k_wpair<<<(64 * 64 + 255) / 256, 256, 0, stream>>>(w2, wtA2, wtD2, 64, 64);
    k_wpair<<<(128 * 64 + 255) / 256, 256, 0, stream>>>(w3, wtA3, wtD3, 128, 64);
    k_wpair<<<(256 * 128 + 255) / 256, 256, 0, stream>>>(w4, wtA4, wtD4, 256, 128);

    auto layer = [&](auto cTag, auto coTag, const float* F, int FS,
                     const float* wtA, const float* wtD,
                     const float* sc, const float* bi, float* outp) {
        constexpr int C  = decltype(cTag)::value;
        constexpr int CO = decltype(coTag)::value;
        k_xx<C><<<(BB * NN + 255) / 256, 256, 0, stream>>>(F, FS, xx);
        for (int b0 = 0; b0 < BB; b0 += nbD) {
            int nb = BB - b0 < nbD ? BB - b0 : nbD;
            k_dist<C><<<nb * 1024, 256, 0, stream>>>(F, FS, xx, b0, D);
            k_select<<<nb * 512, 256, 0, stream>>>(D, idx, b0);
        }
        // transform + gather, batch-chunked to fit union region
        size_t ypb = (size_t)NN * CO * 4;          // bytes per batch per buffer
        int nbY = (int)(avail / (2 * ypb));
        if (nbY < 1) nbY = 1;
        if (nbY > BB) nbY = BB;
        for (int b0 = 0; b0 < BB; b0 += nbY) {
            int nb = BB - b0 < nbY ? BB - b0 : nbY;
            float* Yc  = (float*)uni;
            float* C2c = Yc + (size_t)nb * NN * CO;
            dim3 g((nb * NN) / 64, CO / 64);
            k_gemm_pair<C, CO><<<g, 256, 0, stream>>>(F, FS, b0, wtA, wtD, Yc, C2c);
            constexpr int PPB = 4 * (64 / (CO / 4));
            k_gather<CO><<<(nb * NN) / PPB, 256, 0, stream>>>(Yc, C2c, idx, sc, bi, outp, 512, b0);
        }
    };

    auto ic = [](auto v) { return v; };
    layer(std::integral_constant<int, 3>{},   std::integral_constant<int, 64>{},  xt,         3,   wtA1, wtD1, s1, b1, xcat + 0);
    layer(std::integral_constant<int, 64>{},  std::integral_constant<int, 64>{},  xcat + 0,   512, wtA2, wtD2, s2, b2, xcat + 64);
    layer(std::integral_constant<int, 64>{},  std::integral_constant<int, 128>{}, xcat + 64,  512, wtA3, wtD3, s3, b3, xcat + 128);
    layer(std::integral_constant<int, 128>{}, std::integral_constant<int, 256>{}, xcat + 128, 512, wtA4, wtD4, s4, b4, xcat + 256);
    (void)ic;

    // head (union region now holds w5t/pmax/psum/pooled/f1/f2)
    k_transpose_w<<<(1024 * 512 + 255) / 256, 256, 0, stream>>>(w5, w5t, 1024, 512);
    dim3 g5((BB * NN) / 64, 1024 / 128);
    k_conv5<<<g5, 256, 0, stream>>>(xcat, w5t, s5, b5, pmax, psum);
    k_poolreduce<<<(BB * 1024 + 255) / 256, 256, 0, stream>>>(pmax, psum, pooled);
    k_fc<<<(BB * 512 + 255) / 256, 256, 0, stream>>>(pooled, fc1w, s6, b6, f1, 2048, 512, 1);
    k_fc<<<(BB * 256 + 255) / 256, 256, 0, stream>>>(f1, fc2w, s7, b7, f2, 512, 256, 1);
    k_fc<<<(BB * 40 + 255) / 256, 256, 0, stream>>>(f2, fc3w, nullptr, fc3b, out, 256, 40, 0);
}

// Round 4
// 1128.289 us; speedup vs baseline: 6.0179x; 1.3134x over previous
//
#include <hip/hip_runtime.h>
#include <float.h>
#include <type_traits>

#define BB 8
#define NN 2048
#define KNN 20

__device__ __forceinline__ float leaky(float v) { return fmaxf(v, 0.2f * v); }

// ---------- transpose x (B,3,N) -> xt (B,N,3) ----------
__global__ void k_transpose_x(const float* __restrict__ x, float* __restrict__ xt) {
    int i = blockIdx.x * 256 + threadIdx.x;
    if (i >= BB * NN * 3) return;
    int c = i % 3; int n = (i / 3) % NN; int b = i / (3 * NN);
    xt[i] = x[((size_t)b * 3 + c) * NN + n];
}

// ---------- LDS-tiled transpose w (CO,CI) -> wt (CI,CO), 64x64 tiles ----------
__global__ __launch_bounds__(256) void k_transpose_w_tiled(const float* __restrict__ w,
                                                           float* __restrict__ wt,
                                                           int CO, int CI) {
    __shared__ float tile[64][65];
    int o0 = blockIdx.x * 64;
    int c0 = blockIdx.y * 64;
    int tid = threadIdx.x;
    for (int i = tid; i < 64 * 64; i += 256) {
        int r = i >> 6, c = i & 63;
        tile[r][c] = w[(size_t)(o0 + r) * CI + c0 + c];
    }
    __syncthreads();
    for (int i = tid; i < 64 * 64; i += 256) {
        int cc = i >> 6, oo = i & 63;
        wt[(size_t)(c0 + cc) * CO + o0 + oo] = tile[oo][cc];
    }
}

// ---------- edgeconv weight split: w (CO, 2*CI) -> wtA (CI,CO), wtD (CI,CO) ----------
__global__ void k_wpair(const float* __restrict__ w, float* __restrict__ wtA,
                        float* __restrict__ wtD, int CO, int CI) {
    int i = blockIdx.x * 256 + threadIdx.x;
    if (i >= CO * CI) return;
    int o = i / CI, c = i % CI;
    float a = w[(size_t)o * 2 * CI + c];
    float bb = w[(size_t)o * 2 * CI + CI + c];
    wtA[c * CO + o] = a;
    wtD[c * CO + o] = bb - a;
}

// ---------- squared norms per point ----------
template<int C>
__global__ void k_xx(const float* __restrict__ F, int FS, float* __restrict__ xx) {
    int i = blockIdx.x * 256 + threadIdx.x;
    if (i >= BB * NN) return;
    const float* r = F + (size_t)i * FS;
    float s = 0.f;
    #pragma unroll
    for (int c = 0; c < C; ++c) { float v = r[c]; s += v * v; }
    xx[i] = s;
}

// ---------- distance matrix: D[bl][n][m] = 2*dot - xx[n] - xx[m]; c-chunked LDS ----------
template<int C>
__global__ __launch_bounds__(256) void k_dist(const float* __restrict__ F, int FS,
                                              const float* __restrict__ xx, int b0,
                                              float* __restrict__ D) {
    constexpr int CCH = (C >= 32) ? 32 : C;
    constexpr int NCH = C / CCH;
    __shared__ __align__(16) float Xi[CCH * 64];
    __shared__ __align__(16) float Xj[CCH * 64];
    int tid = threadIdx.x;
    int bl = blockIdx.x >> 10;
    int t  = blockIdx.x & 1023;
    int i0 = (t >> 5) * 64, j0 = (t & 31) * 64;
    int b = b0 + bl;
    const float* Fb = F + (size_t)b * NN * FS;
    int ty = tid >> 4, tx = tid & 15;
    float acc[4][4] = {};
    for (int ch = 0; ch < NCH; ++ch) {
        int cb = ch * CCH;
        if (ch) __syncthreads();
        if constexpr (CCH % 4 == 0) {
            for (int k = tid; k < 64 * (CCH / 4); k += 256) {
                int r = k & 63, cc = k >> 6;
                float vi[4], vj[4];
                *(float4*)vi = *(const float4*)(Fb + (size_t)(i0 + r) * FS + cb + 4 * cc);
                *(float4*)vj = *(const float4*)(Fb + (size_t)(j0 + r) * FS + cb + 4 * cc);
                #pragma unroll
                for (int u = 0; u < 4; ++u) {
                    Xi[(4 * cc + u) * 64 + r] = vi[u];
                    Xj[(4 * cc + u) * 64 + r] = vj[u];
                }
            }
        } else {
            for (int k = tid; k < 64 * CCH; k += 256) {
                int r = k & 63, c = k >> 6;
                Xi[c * 64 + r] = Fb[(size_t)(i0 + r) * FS + cb + c];
                Xj[c * 64 + r] = Fb[(size_t)(j0 + r) * FS + cb + c];
            }
        }
        __syncthreads();
        for (int c = 0; c < CCH; ++c) {
            float a[4], bv[4];
            *(float4*)a  = *(const float4*)&Xi[c * 64 + 4 * ty];
            *(float4*)bv = *(const float4*)&Xj[c * 64 + 4 * tx];
            #pragma unroll
            for (int r = 0; r < 4; ++r)
                #pragma unroll
                for (int s = 0; s < 4; ++s) acc[r][s] += a[r] * bv[s];
        }
    }
    const float* xxb = xx + (size_t)b * NN;
    float xxi[4], xxj[4];
    #pragma unroll
    for (int r = 0; r < 4; ++r) xxi[r] = xxb[i0 + 4 * ty + r];
    #pragma unroll
    for (int s = 0; s < 4; ++s) xxj[s] = xxb[j0 + 4 * tx + s];
    float* Dp = D + (size_t)bl * NN * NN;
    #pragma unroll
    for (int r = 0; r < 4; ++r) {
        float ov[4];
        #pragma unroll
        for (int s = 0; s < 4; ++s) ov[s] = 2.f * acc[r][s] - xxi[r] - xxj[s];
        *(float4*)(Dp + (size_t)(i0 + 4 * ty + r) * NN + j0 + 4 * tx) = *(float4*)ov;
    }
}

// ---------- top-20 selection: one wave per query, row in registers ----------
__global__ __launch_bounds__(256) void k_select(const float* __restrict__ D,
                                                int* __restrict__ idxo, int b0) {
    int tid = threadIdx.x;
    int lane = tid & 63;
    int w = (blockIdx.x << 2) + (tid >> 6);
    int bl = w / NN, n = w % NN;
    const float* row = D + (size_t)w * NN;
    float d[32];
    #pragma unroll
    for (int q = 0; q < 8; ++q)
        *(float4*)&d[4 * q] = *(const float4*)(row + 4 * lane + 256 * q);
    float bv = d[0]; int bj = 0;
    #pragma unroll
    for (int j = 1; j < 32; ++j) if (d[j] > bv) { bv = d[j]; bj = j; }
    int* op = idxo + ((size_t)(b0 + bl) * NN + n) * KNN;
    for (int k = 0; k < KNN; ++k) {
        float rv = bv;
        int rm = 4 * lane + 256 * (bj >> 2) + (bj & 3);
        #pragma unroll
        for (int s = 1; s < 64; s <<= 1) {
            float ov = __shfl_xor(rv, s);
            int om = __shfl_xor(rm, s);
            if (ov > rv || (ov == rv && om < rm)) { rv = ov; rm = om; }
        }
        if (lane == 0) op[k] = rm;
        if (((rm >> 2) & 63) == lane) {
            int oj = ((rm >> 8) << 2) | (rm & 3);
            #pragma unroll
            for (int j = 0; j < 32; ++j) if (j == oj) d[j] = -FLT_MAX;
            bv = d[0]; bj = 0;
            #pragma unroll
            for (int j = 1; j < 32; ++j) if (d[j] > bv) { bv = d[j]; bj = j; }
        }
    }
}

// ---------- pair GEMM: Y = F*wtA, C2 = F*wtD  (64 rows x 64 cols per block) ----------
template<int CIN, int COUT>
__global__ __launch_bounds__(256) void k_gemm_pair(const float* __restrict__ F, int FS, int b0,
    const float* __restrict__ wtA, const float* __restrict__ wtD,
    float* __restrict__ Y, float* __restrict__ C2) {
    constexpr int CCH = (CIN >= 32) ? 32 : CIN;
    constexpr int NCH = CIN / CCH;
    __shared__ __align__(16) float Xi[CCH * 64];
    __shared__ __align__(16) float Wa[CCH * 64];
    __shared__ __align__(16) float Wd[CCH * 64];
    int tid = threadIdx.x;
    int r0 = blockIdx.x * 64;
    int c0 = blockIdx.y * 64;
    int b = b0 + r0 / NN;
    int n0 = r0 % NN;
    const float* Fb = F + ((size_t)b * NN + n0) * FS;
    int ty = tid >> 4, tx = tid & 15;
    float accY[4][4] = {}, accD[4][4] = {};
    for (int ch = 0; ch < NCH; ++ch) {
        int cb = ch * CCH;
        if (ch) __syncthreads();
        if constexpr (CCH % 4 == 0) {
            for (int t = tid; t < 64 * (CCH / 4); t += 256) {
                int r = t & 63, cc = t >> 6;
                float v[4];
                *(float4*)v = *(const float4*)(Fb + (size_t)r * FS + cb + 4 * cc);
                #pragma unroll
                for (int u = 0; u < 4; ++u) Xi[(4 * cc + u) * 64 + r] = v[u];
            }
            for (int t = tid; t < CCH * 16; t += 256) {
                int c = t >> 4, q = t & 15;
                *(float4*)&Wa[c * 64 + 4 * q] = *(const float4*)(wtA + (size_t)(cb + c) * COUT + c0 + 4 * q);
                *(float4*)&Wd[c * 64 + 4 * q] = *(const float4*)(wtD + (size_t)(cb + c) * COUT + c0 + 4 * q);
            }
        } else {
            for (int t = tid; t < 64 * CCH; t += 256) {
                int r = t & 63, c = t >> 6;
                Xi[c * 64 + r] = Fb[(size_t)r * FS + cb + c];
            }
            for (int t = tid; t < CCH * 64; t += 256) {
                int col = t & 63, c = t >> 6;
                Wa[c * 64 + col] = wtA[(size_t)(cb + c) * COUT + c0 + col];
                Wd[c * 64 + col] = wtD[(size_t)(cb + c) * COUT + c0 + col];
            }
        }
        __syncthreads();
        for (int c = 0; c < CCH; ++c) {
            float a[4], wa[4], wd[4];
            *(float4*)a  = *(const float4*)&Xi[c * 64 + 4 * ty];
            *(float4*)wa = *(const float4*)&Wa[c * 64 + 4 * tx];
            *(float4*)wd = *(const float4*)&Wd[c * 64 + 4 * tx];
            #pragma unroll
            for (int r = 0; r < 4; ++r)
                #pragma unroll
                for (int s = 0; s < 4; ++s) {
                    accY[r][s] += a[r] * wa[s];
                    accD[r][s] += a[r] * wd[s];
                }
        }
    }
    #pragma unroll
    for (int r = 0; r < 4; ++r) {
        size_t ro = (size_t)(r0 + 4 * ty + r) * COUT + c0 + 4 * tx;
        *(float4*)(Y  + ro) = *(float4*)accY[r];
        *(float4*)(C2 + ro) = *(float4*)accD[r];
    }
}

// ---------- gather-max: out[p][o] = max_k leaky((Y[idx[p][k]][o] + C2[p][o])*s + b) ----------
template<int COUT>
__global__ __launch_bounds__(256) void k_gather(const float* __restrict__ Y,
    const float* __restrict__ C2, const int* __restrict__ idx,
    const float* __restrict__ sc, const float* __restrict__ bi,
    float* __restrict__ out, int OS, int b0) {
    constexpr int LPP = COUT / 4;
    constexpr int PPW = 64 / LPP;
    constexpr int PPB = 4 * PPW;
    int tid = threadIdx.x;
    int lane = tid & 63, wv = tid >> 6;
    int pl = blockIdx.x * PPB + wv * PPW + lane / LPP;
    int bl = pl / NN, n = pl % NN;
    int o0 = 4 * (lane % LPP);
    float c2[4], s4[4], b4[4];
    *(float4*)c2 = *(const float4*)(C2 + (size_t)pl * COUT + o0);
    *(float4*)s4 = *(const float4*)(sc + o0);
    *(float4*)b4 = *(const float4*)(bi + o0);
    const int* ip = idx + ((size_t)(b0 + bl) * NN + n) * KNN;
    const float* Yb = Y + (size_t)bl * NN * COUT;
    float mx[4] = {-FLT_MAX, -FLT_MAX, -FLT_MAX, -FLT_MAX};
    for (int k = 0; k < KNN; ++k) {
        int m = ip[k];
        float y[4];
        *(float4*)y = *(const float4*)(Yb + (size_t)m * COUT + o0);
        #pragma unroll
        for (int u = 0; u < 4; ++u) {
            float v = (y[u] + c2[u]) * s4[u] + b4[u];
            mx[u] = fmaxf(mx[u], leaky(v));
        }
    }
    float* op = out + ((size_t)(b0 + bl) * NN + n) * OS + o0;
    *(float4*)op = *(float4*)mx;
}

// ---------- conv5: 16384x1024x512 GEMM, 64x128 tile, fused partial max/sum pooling ----------
__global__ __launch_bounds__(256) void k_conv5(const float* __restrict__ xcat,
    const float* __restrict__ w5t, const float* __restrict__ s5, const float* __restrict__ b5,
    float* __restrict__ pmax, float* __restrict__ psum) {
    __shared__ __align__(16) float Xi[32 * 64];
    __shared__ __align__(16) float Wj[32 * 128];
    int tid = threadIdx.x;
    int ty = tid >> 4, tx = tid & 15;
    int r0 = blockIdx.x * 64;
    int col0 = blockIdx.y * 128;
    int b = r0 / NN, tileInB = (r0 % NN) / 64;
    const float* Fb = xcat + (size_t)r0 * 512;
    float acc[4][8] = {};
    for (int ch = 0; ch < 16; ++ch) {
        int cb = ch * 32;
        if (ch) __syncthreads();
        for (int t = tid; t < 64 * 8; t += 256) {
            int r = t & 63, cc = t >> 6;
            float v[4];
            *(float4*)v = *(const float4*)(Fb + (size_t)r * 512 + cb + 4 * cc);
            #pragma unroll
            for (int u = 0; u < 4; ++u) Xi[(4 * cc + u) * 64 + r] = v[u];
        }
        for (int t = tid; t < 32 * 32; t += 256) {
            int c = t >> 5, q = t & 31;
            *(float4*)&Wj[c * 128 + 4 * q] = *(const float4*)(w5t + (size_t)(cb + c) * 1024 + col0 + 4 * q);
        }
        __syncthreads();
        for (int c = 0; c < 32; ++c) {
            float a[4], w[8];
            *(float4*)a       = *(const float4*)&Xi[c * 64 + 4 * ty];
            *(float4*)w       = *(const float4*)&Wj[c * 128 + 8 * tx];
            *(float4*)(w + 4) = *(const float4*)&Wj[c * 128 + 8 * tx + 4];
            #pragma unroll
            for (int r = 0; r < 4; ++r)
                #pragma unroll
                for (int u = 0; u < 8; ++u) acc[r][u] += a[r] * w[u];
        }
    }
    float hmx[8], hsm[8];
    #pragma unroll
    for (int u = 0; u < 8; ++u) { hmx[u] = -FLT_MAX; hsm[u] = 0.f; }
    #pragma unroll
    for (int u = 0; u < 8; ++u) {
        int o = col0 + 8 * tx + u;
        float sv = s5[o], bv = b5[o];
        #pragma unroll
        for (int r = 0; r < 4; ++r) {
            float h = leaky(acc[r][u] * sv + bv);
            hmx[u] = fmaxf(hmx[u], h);
            hsm[u] += h;
        }
    }
    __syncthreads();
    float* redM = Xi;
    float* redS = Wj;
    #pragma unroll
    for (int u = 0; u < 8; ++u) {
        redM[ty * 128 + 8 * tx + u] = hmx[u];
        redS[ty * 128 + 8 * tx + u] = hsm[u];
    }
    __syncthreads();
    for (int s = 8; s > 0; s >>= 1) {
        if (ty < s) {
            #pragma unroll
            for (int u = 0; u < 8; ++u) {
                int c = 8 * tx + u;
                redM[ty * 128 + c] = fmaxf(redM[ty * 128 + c], redM[(ty + s) * 128 + c]);
                redS[ty * 128 + c] += redS[(ty + s) * 128 + c];
            }
        }
        __syncthreads();
    }
    if (ty == 0) {
        #pragma unroll
        for (int u = 0; u < 8; ++u) {
            int c = 8 * tx + u;
            size_t o = ((size_t)b * 32 + tileInB) * 1024 + col0 + c;
            pmax[o] = redM[c];
            psum[o] = redS[c];
        }
    }
}

__global__ void k_poolreduce(const float* __restrict__ pmax, const float* __restrict__ psum,
                             float* __restrict__ pooled) {
    int i = blockIdx.x * 256 + threadIdx.x;
    if (i >= BB * 1024) return;
    int b = i / 1024, o = i % 1024;
    float mx = -FLT_MAX, sm = 0.f;
    for (int ch = 0; ch < 32; ++ch) {
        mx = fmaxf(mx, pmax[((size_t)b * 32 + ch) * 1024 + o]);
        sm += psum[((size_t)b * 32 + ch) * 1024 + o];
    }
    pooled[(size_t)b * 2048 + o] = mx;
    pooled[(size_t)b * 2048 + 1024 + o] = sm / (float)NN;
}

// ---------- FC: wave-per-output, coalesced float4 weight reads, shfl reduce ----------
template<int CI, bool SCALE, bool RELU>
__global__ __launch_bounds__(256) void k_fcw(const float* __restrict__ in,
                                             const float* __restrict__ w,
                                             const float* __restrict__ sc,
                                             const float* __restrict__ bi,
                                             float* __restrict__ out, int CO) {
    int wv = (blockIdx.x << 2) + (threadIdx.x >> 6);   // global wave id = b*CO + o
    int lane = threadIdx.x & 63;
    int o = wv % CO, b = wv / CO;
    const float* ir = in + (size_t)b * CI;
    const float* wr = w + (size_t)o * CI;
    float acc = 0.f;
    #pragma unroll
    for (int q = 0; q < CI / 256; ++q) {
        int ofs = q * 256 + 4 * lane;
        float4 wv4 = *(const float4*)(wr + ofs);
        float4 iv4 = *(const float4*)(ir + ofs);
        acc += wv4.x * iv4.x + wv4.y * iv4.y + wv4.z * iv4.z + wv4.w * iv4.w;
    }
    #pragma unroll
    for (int s = 1; s < 64; s <<= 1) acc += __shfl_xor(acc, s);
    if (lane == 0) {
        float v = SCALE ? (acc * sc[o] + bi[o]) : (acc + bi[o]);
        if (RELU) v = fmaxf(v, 0.f);
        out[wv] = v;
    }
}

extern "C" void kernel_launch(void* const* d_in, const int* in_sizes, int n_in,
                              void* d_out, int out_size, void* d_ws, size_t ws_size,
                              hipStream_t stream) {
    const float* x    = (const float*)d_in[0];
    const float* w1   = (const float*)d_in[1];
    const float* s1   = (const float*)d_in[2];
    const float* b1   = (const float*)d_in[3];
    const float* w2   = (const float*)d_in[4];
    const float* s2   = (const float*)d_in[5];
    const float* b2   = (const float*)d_in[6];
    const float* w3   = (const float*)d_in[7];
    const float* s3   = (const float*)d_in[8];
    const float* b3   = (const float*)d_in[9];
    const float* w4   = (const float*)d_in[10];
    const float* s4   = (const float*)d_in[11];
    const float* b4   = (const float*)d_in[12];
    const float* w5   = (const float*)d_in[13];
    const float* s5   = (const float*)d_in[14];
    const float* b5   = (const float*)d_in[15];
    const float* fc1w = (const float*)d_in[16];
    const float* s6   = (const float*)d_in[17];
    const float* b6   = (const float*)d_in[18];
    const float* fc2w = (const float*)d_in[19];
    const float* s7   = (const float*)d_in[20];
    const float* b7   = (const float*)d_in[21];
    const float* fc3w = (const float*)d_in[22];
    const float* fc3b = (const float*)d_in[23];
    float* out = (float*)d_out;

    char* ws = (char*)d_ws;
    size_t off = 0;
    auto alloc = [&](size_t bytes) {
        void* p = ws + off;
        off = (off + bytes + 255) & ~(size_t)255;
        return p;
    };
    float* xt   = (float*)alloc((size_t)BB * NN * 3 * 4);
    float* xcat = (float*)alloc((size_t)BB * NN * 512 * 4);
    int*   idx  = (int*)  alloc((size_t)BB * NN * KNN * 4);
    float* xx   = (float*)alloc((size_t)BB * NN * 4);
    float* wtA1 = (float*)alloc(3 * 64 * 4);
    float* wtD1 = (float*)alloc(3 * 64 * 4);
    float* wtA2 = (float*)alloc(64 * 64 * 4);
    float* wtD2 = (float*)alloc(64 * 64 * 4);
    float* wtA3 = (float*)alloc(64 * 128 * 4);
    float* wtD3 = (float*)alloc(64 * 128 * 4);
    float* wtA4 = (float*)alloc(128 * 256 * 4);
    float* wtD4 = (float*)alloc(128 * 256 * 4);
    size_t base_end = off;

    // UNION region: D (dist phase) / Y+C2 (transform phase) / head buffers
    const size_t D1 = (size_t)NN * NN * 4;
    size_t avail = ws_size > base_end ? ws_size - base_end : 0;
    int nbD = (int)(avail / D1);
    if (nbD < 1) nbD = 1;
    if (nbD > BB) nbD = BB;
    char* uni = ws + base_end;
    float* D      = (float*)uni;
    float* w5t    = (float*)uni;
    float* pmax   = w5t + 512 * 1024;
    float* psum   = pmax + (size_t)BB * 32 * 1024;
    float* pooled = psum + (size_t)BB * 32 * 1024;
    float* f1     = pooled + (size_t)BB * 2048;
    float* f2     = f1 + (size_t)BB * 512;

    k_transpose_x<<<(BB * NN * 3 + 255) / 256, 256, 0, stream>>>(x, xt);
    k_wpair<<<(64 * 3 + 255) / 256, 256, 0, stream>>>(w1, wtA1, wtD1, 64, 3);
    k_wpair<<<(64 * 64 + 255) / 256, 256, 0, stream>>>(w2, wtA2, wtD2, 64, 64);
    k_wpair<<<(128 * 64 + 255) / 256, 256, 0, stream>>>(w3, wtA3, wtD3, 128, 64);
    k_wpair<<<(256 * 128 + 255) / 256, 256, 0, stream>>>(w4, wtA4, wtD4, 256, 128);

    auto layer = [&](auto cTag, auto coTag, const float* F, int FS,
                     const float* wtA, const float* wtD,
                     const float* sc, const float* bi, float* outp) {
        constexpr int C  = decltype(cTag)::value;
        constexpr int CO = decltype(coTag)::value;
        k_xx<C><<<(BB * NN + 255) / 256, 256, 0, stream>>>(F, FS, xx);
        for (int b0 = 0; b0 < BB; b0 += nbD) {
            int nb = BB - b0 < nbD ? BB - b0 : nbD;
            k_dist<C><<<nb * 1024, 256, 0, stream>>>(F, FS, xx, b0, D);
            k_select<<<nb * 512, 256, 0, stream>>>(D, idx, b0);
        }
        size_t ypb = (size_t)NN * CO * 4;
        int nbY = (int)(avail / (2 * ypb));
        if (nbY < 1) nbY = 1;
        if (nbY > BB) nbY = BB;
        for (int b0 = 0; b0 < BB; b0 += nbY) {
            int nb = BB - b0 < nbY ? BB - b0 : nbY;
            float* Yc  = (float*)uni;
            float* C2c = Yc + (size_t)nb * NN * CO;
            dim3 g((nb * NN) / 64, CO / 64);
            k_gemm_pair<C, CO><<<g, 256, 0, stream>>>(F, FS, b0, wtA, wtD, Yc, C2c);
            constexpr int PPB = 4 * (64 / (CO / 4));
            k_gather<CO><<<(nb * NN) / PPB, 256, 0, stream>>>(Yc, C2c, idx, sc, bi, outp, 512, b0);
        }
    };

    layer(std::integral_constant<int, 3>{},   std::integral_constant<int, 64>{},  xt,         3,   wtA1, wtD1, s1, b1, xcat + 0);
    layer(std::integral_constant<int, 64>{},  std::integral_constant<int, 64>{},  xcat + 0,   512, wtA2, wtD2, s2, b2, xcat + 64);
    layer(std::integral_constant<int, 64>{},  std::integral_constant<int, 128>{}, xcat + 64,  512, wtA3, wtD3, s3, b3, xcat + 128);
    layer(std::integral_constant<int, 128>{}, std::integral_constant<int, 256>{}, xcat + 128, 512, wtA4, wtD4, s4, b4, xcat + 256);

    // head (union region now holds w5t/pmax/psum/pooled/f1/f2)
    dim3 gt(1024 / 64, 512 / 64);
    k_transpose_w_tiled<<<gt, 256, 0, stream>>>(w5, w5t, 1024, 512);
    dim3 g5((BB * NN) / 64, 1024 / 128);
    k_conv5<<<g5, 256, 0, stream>>>(xcat, w5t, s5, b5, pmax, psum);
    k_poolreduce<<<(BB * 1024 + 255) / 256, 256, 0, stream>>>(pmax, psum, pooled);
    k_fcw<2048, true,  true ><<<(BB * 512) / 4, 256, 0, stream>>>(pooled, fc1w, s6, b6, f1, 512);
    k_fcw<512,  true,  true ><<<(BB * 256) / 4, 256, 0, stream>>>(f1, fc2w, s7, b7, f2, 256);
    k_fcw<256,  false, false><<<(BB * 40)  / 4, 256, 0, stream>>>(f2, fc3w, nullptr, fc3b, out, 40);
}

// Round 5
// 1114.998 us; speedup vs baseline: 6.0896x; 1.0119x over previous
//
#include <hip/hip_runtime.h>
#include <float.h>
#include <type_traits>

#define BB 8
#define NN 2048
#define KNN 20

__device__ __forceinline__ float leaky(float v) { return fmaxf(v, 0.2f * v); }

// ---------- transpose x (B,3,N) -> xt (B,N,3) ----------
__global__ void k_transpose_x(const float* __restrict__ x, float* __restrict__ xt) {
    int i = blockIdx.x * 256 + threadIdx.x;
    if (i >= BB * NN * 3) return;
    int c = i % 3; int n = (i / 3) % NN; int b = i / (3 * NN);
    xt[i] = x[((size_t)b * 3 + c) * NN + n];
}

// ---------- LDS-tiled transpose w (CO,CI) -> wt (CI,CO), 64x64 tiles ----------
__global__ __launch_bounds__(256) void k_transpose_w_tiled(const float* __restrict__ w,
                                                           float* __restrict__ wt,
                                                           int CO, int CI) {
    __shared__ float tile[64][65];
    int o0 = blockIdx.x * 64;
    int c0 = blockIdx.y * 64;
    int tid = threadIdx.x;
    for (int i = tid; i < 64 * 64; i += 256) {
        int r = i >> 6, c = i & 63;
        tile[r][c] = w[(size_t)(o0 + r) * CI + c0 + c];
    }
    __syncthreads();
    for (int i = tid; i < 64 * 64; i += 256) {
        int cc = i >> 6, oo = i & 63;
        wt[(size_t)(c0 + cc) * CO + o0 + oo] = tile[oo][cc];
    }
}

// ---------- edgeconv weight split: w (CO, 2*CI) -> wtA (CI,CO), wtD (CI,CO) ----------
__global__ void k_wpair(const float* __restrict__ w, float* __restrict__ wtA,
                        float* __restrict__ wtD, int CO, int CI) {
    int i = blockIdx.x * 256 + threadIdx.x;
    if (i >= CO * CI) return;
    int o = i / CI, c = i % CI;
    float a = w[(size_t)o * 2 * CI + c];
    float bb = w[(size_t)o * 2 * CI + CI + c];
    wtA[c * CO + o] = a;
    wtD[c * CO + o] = bb - a;
}

// ---------- squared norms per point ----------
template<int C>
__global__ void k_xx(const float* __restrict__ F, int FS, float* __restrict__ xx) {
    int i = blockIdx.x * 256 + threadIdx.x;
    if (i >= BB * NN) return;
    const float* r = F + (size_t)i * FS;
    float s = 0.f;
    #pragma unroll
    for (int c = 0; c < C; ++c) { float v = r[c]; s += v * v; }
    xx[i] = s;
}

// ---------- distance matrix: D[bl][n][m] = 2*dot - xx[n] - xx[m]; c-chunked LDS ----------
template<int C>
__global__ __launch_bounds__(256) void k_dist(const float* __restrict__ F, int FS,
                                              const float* __restrict__ xx, int b0,
                                              float* __restrict__ D) {
    constexpr int CCH = (C >= 32) ? 32 : C;
    constexpr int NCH = C / CCH;
    __shared__ __align__(16) float Xi[CCH * 64];
    __shared__ __align__(16) float Xj[CCH * 64];
    int tid = threadIdx.x;
    int bl = blockIdx.x >> 10;
    int t  = blockIdx.x & 1023;
    int i0 = (t >> 5) * 64, j0 = (t & 31) * 64;
    int b = b0 + bl;
    const float* Fb = F + (size_t)b * NN * FS;
    int ty = tid >> 4, tx = tid & 15;
    float acc[4][4] = {};
    for (int ch = 0; ch < NCH; ++ch) {
        int cb = ch * CCH;
        if (ch) __syncthreads();
        if constexpr (CCH % 4 == 0) {
            for (int k = tid; k < 64 * (CCH / 4); k += 256) {
                int r = k & 63, cc = k >> 6;
                float vi[4], vj[4];
                *(float4*)vi = *(const float4*)(Fb + (size_t)(i0 + r) * FS + cb + 4 * cc);
                *(float4*)vj = *(const float4*)(Fb + (size_t)(j0 + r) * FS + cb + 4 * cc);
                #pragma unroll
                for (int u = 0; u < 4; ++u) {
                    Xi[(4 * cc + u) * 64 + r] = vi[u];
                    Xj[(4 * cc + u) * 64 + r] = vj[u];
                }
            }
        } else {
            for (int k = tid; k < 64 * CCH; k += 256) {
                int r = k & 63, c = k >> 6;
                Xi[c * 64 + r] = Fb[(size_t)(i0 + r) * FS + cb + c];
                Xj[c * 64 + r] = Fb[(size_t)(j0 + r) * FS + cb + c];
            }
        }
        __syncthreads();
        for (int c = 0; c < CCH; ++c) {
            float a[4], bv[4];
            *(float4*)a  = *(const float4*)&Xi[c * 64 + 4 * ty];
            *(float4*)bv = *(const float4*)&Xj[c * 64 + 4 * tx];
            #pragma unroll
            for (int r = 0; r < 4; ++r)
                #pragma unroll
                for (int s = 0; s < 4; ++s) acc[r][s] += a[r] * bv[s];
        }
    }
    const float* xxb = xx + (size_t)b * NN;
    float xxi[4], xxj[4];
    #pragma unroll
    for (int r = 0; r < 4; ++r) xxi[r] = xxb[i0 + 4 * ty + r];
    #pragma unroll
    for (int s = 0; s < 4; ++s) xxj[s] = xxb[j0 + 4 * tx + s];
    float* Dp = D + (size_t)bl * NN * NN;
    #pragma unroll
    for (int r = 0; r < 4; ++r) {
        float ov[4];
        #pragma unroll
        for (int s = 0; s < 4; ++s) ov[s] = 2.f * acc[r][s] - xxi[r] - xxj[s];
        *(float4*)(Dp + (size_t)(i0 + 4 * ty + r) * NN + j0 + 4 * tx) = *(float4*)ov;
    }
}

// ---------- top-20 selection: one wave per query, row in registers ----------
__global__ __launch_bounds__(256) void k_select(const float* __restrict__ D,
                                                int* __restrict__ idxo, int b0) {
    int tid = threadIdx.x;
    int lane = tid & 63;
    int w = (blockIdx.x << 2) + (tid >> 6);
    int bl = w / NN, n = w % NN;
    const float* row = D + (size_t)w * NN;
    float d[32];
    #pragma unroll
    for (int q = 0; q < 8; ++q)
        *(float4*)&d[4 * q] = *(const float4*)(row + 4 * lane + 256 * q);
    float bv = d[0]; int bj = 0;
    #pragma unroll
    for (int j = 1; j < 32; ++j) if (d[j] > bv) { bv = d[j]; bj = j; }
    int* op = idxo + ((size_t)(b0 + bl) * NN + n) * KNN;
    for (int k = 0; k < KNN; ++k) {
        float rv = bv;
        int rm = 4 * lane + 256 * (bj >> 2) + (bj & 3);
        #pragma unroll
        for (int s = 1; s < 64; s <<= 1) {
            float ov = __shfl_xor(rv, s);
            int om = __shfl_xor(rm, s);
            if (ov > rv || (ov == rv && om < rm)) { rv = ov; rm = om; }
        }
        if (lane == 0) op[k] = rm;
        if (((rm >> 2) & 63) == lane) {
            int oj = ((rm >> 8) << 2) | (rm & 3);
            #pragma unroll
            for (int j = 0; j < 32; ++j) if (j == oj) d[j] = -FLT_MAX;
            bv = d[0]; bj = 0;
            #pragma unroll
            for (int j = 1; j < 32; ++j) if (d[j] > bv) { bv = d[j]; bj = j; }
        }
    }
}

// ---------- pair GEMM: Y = F*wtA, C2 = F*wtD  (64 rows x 64 cols per block) ----------
template<int CIN, int COUT>
__global__ __launch_bounds__(256) void k_gemm_pair(const float* __restrict__ F, int FS, int b0,
    const float* __restrict__ wtA, const float* __restrict__ wtD,
    float* __restrict__ Y, float* __restrict__ C2) {
    constexpr int CCH = (CIN >= 32) ? 32 : CIN;
    constexpr int NCH = CIN / CCH;
    __shared__ __align__(16) float Xi[CCH * 64];
    __shared__ __align__(16) float Wa[CCH * 64];
    __shared__ __align__(16) float Wd[CCH * 64];
    int tid = threadIdx.x;
    int r0 = blockIdx.x * 64;
    int c0 = blockIdx.y * 64;
    int b = b0 + r0 / NN;
    int n0 = r0 % NN;
    const float* Fb = F + ((size_t)b * NN + n0) * FS;
    int ty = tid >> 4, tx = tid & 15;
    float accY[4][4] = {}, accD[4][4] = {};
    for (int ch = 0; ch < NCH; ++ch) {
        int cb = ch * CCH;
        if (ch) __syncthreads();
        if constexpr (CCH % 4 == 0) {
            for (int t = tid; t < 64 * (CCH / 4); t += 256) {
                int r = t & 63, cc = t >> 6;
                float v[4];
                *(float4*)v = *(const float4*)(Fb + (size_t)r * FS + cb + 4 * cc);
                #pragma unroll
                for (int u = 0; u < 4; ++u) Xi[(4 * cc + u) * 64 + r] = v[u];
            }
            for (int t = tid; t < CCH * 16; t += 256) {
                int c = t >> 4, q = t & 15;
                *(float4*)&Wa[c * 64 + 4 * q] = *(const float4*)(wtA + (size_t)(cb + c) * COUT + c0 + 4 * q);
                *(float4*)&Wd[c * 64 + 4 * q] = *(const float4*)(wtD + (size_t)(cb + c) * COUT + c0 + 4 * q);
            }
        } else {
            for (int t = tid; t < 64 * CCH; t += 256) {
                int r = t & 63, c = t >> 6;
                Xi[c * 64 + r] = Fb[(size_t)r * FS + cb + c];
            }
            for (int t = tid; t < CCH * 64; t += 256) {
                int col = t & 63, c = t >> 6;
                Wa[c * 64 + col] = wtA[(size_t)(cb + c) * COUT + c0 + col];
                Wd[c * 64 + col] = wtD[(size_t)(cb + c) * COUT + c0 + col];
            }
        }
        __syncthreads();
        for (int c = 0; c < CCH; ++c) {
            float a[4], wa[4], wd[4];
            *(float4*)a  = *(const float4*)&Xi[c * 64 + 4 * ty];
            *(float4*)wa = *(const float4*)&Wa[c * 64 + 4 * tx];
            *(float4*)wd = *(const float4*)&Wd[c * 64 + 4 * tx];
            #pragma unroll
            for (int r = 0; r < 4; ++r)
                #pragma unroll
                for (int s = 0; s < 4; ++s) {
                    accY[r][s] += a[r] * wa[s];
                    accD[r][s] += a[r] * wd[s];
                }
        }
    }
    #pragma unroll
    for (int r = 0; r < 4; ++r) {
        size_t ro = (size_t)(r0 + 4 * ty + r) * COUT + c0 + 4 * tx;
        *(float4*)(Y  + ro) = *(float4*)accY[r];
        *(float4*)(C2 + ro) = *(float4*)accD[r];
    }
}

// ---------- gather-max: out[p][o] = max_k leaky((Y[idx[p][k]][o] + C2[p][o])*s + b) ----------
template<int COUT>
__global__ __launch_bounds__(256) void k_gather(const float* __restrict__ Y,
    const float* __restrict__ C2, const int* __restrict__ idx,
    const float* __restrict__ sc, const float* __restrict__ bi,
    float* __restrict__ out, int OS, int b0) {
    constexpr int LPP = COUT / 4;
    constexpr int PPW = 64 / LPP;
    constexpr int PPB = 4 * PPW;
    int tid = threadIdx.x;
    int lane = tid & 63, wv = tid >> 6;
    int pl = blockIdx.x * PPB + wv * PPW + lane / LPP;
    int bl = pl / NN, n = pl % NN;
    int o0 = 4 * (lane % LPP);
    float c2[4], s4[4], b4[4];
    *(float4*)c2 = *(const float4*)(C2 + (size_t)pl * COUT + o0);
    *(float4*)s4 = *(const float4*)(sc + o0);
    *(float4*)b4 = *(const float4*)(bi + o0);
    const int* ip = idx + ((size_t)(b0 + bl) * NN + n) * KNN;
    const float* Yb = Y + (size_t)bl * NN * COUT;
    float mx[4] = {-FLT_MAX, -FLT_MAX, -FLT_MAX, -FLT_MAX};
    for (int k = 0; k < KNN; ++k) {
        int m = ip[k];
        float y[4];
        *(float4*)y = *(const float4*)(Yb + (size_t)m * COUT + o0);
        #pragma unroll
        for (int u = 0; u < 4; ++u) {
            float v = (y[u] + c2[u]) * s4[u] + b4[u];
            mx[u] = fmaxf(mx[u], leaky(v));
        }
    }
    float* op = out + ((size_t)(b0 + bl) * NN + n) * OS + o0;
    *(float4*)op = *(float4*)mx;
}

// ---------- conv5: 16384x1024x512 GEMM, 64x128 tile, fused partial max/sum pooling ----------
// Bank-conflict-free column split: thread owns cols {col0+4*tx+u} and {col0+64+4*tx+u}
// (16B lane stride = 2-way bank aliasing = free; old 8*tx layout was 4-way conflicted)
__global__ __launch_bounds__(256) void k_conv5(const float* __restrict__ xcat,
    const float* __restrict__ w5t, const float* __restrict__ s5, const float* __restrict__ b5,
    float* __restrict__ pmax, float* __restrict__ psum) {
    __shared__ __align__(16) float Xi[32 * 64];
    __shared__ __align__(16) float Wj[32 * 128];
    int tid = threadIdx.x;
    int ty = tid >> 4, tx = tid & 15;
    int r0 = blockIdx.x * 64;
    int col0 = blockIdx.y * 128;
    int b = r0 / NN, tileInB = (r0 % NN) / 64;
    const float* Fb = xcat + (size_t)r0 * 512;
    float acc[4][2][4] = {};
    for (int ch = 0; ch < 16; ++ch) {
        int cb = ch * 32;
        if (ch) __syncthreads();
        for (int t = tid; t < 64 * 8; t += 256) {
            int r = t & 63, cc = t >> 6;
            float v[4];
            *(float4*)v = *(const float4*)(Fb + (size_t)r * 512 + cb + 4 * cc);
            #pragma unroll
            for (int u = 0; u < 4; ++u) Xi[(4 * cc + u) * 64 + r] = v[u];
        }
        for (int t = tid; t < 32 * 32; t += 256) {
            int c = t >> 5, q = t & 31;
            *(float4*)&Wj[c * 128 + 4 * q] = *(const float4*)(w5t + (size_t)(cb + c) * 1024 + col0 + 4 * q);
        }
        __syncthreads();
        for (int c = 0; c < 32; ++c) {
            float a[4], w0[4], w1[4];
            *(float4*)a  = *(const float4*)&Xi[c * 64 + 4 * ty];
            *(float4*)w0 = *(const float4*)&Wj[c * 128 + 4 * tx];
            *(float4*)w1 = *(const float4*)&Wj[c * 128 + 64 + 4 * tx];
            #pragma unroll
            for (int r = 0; r < 4; ++r)
                #pragma unroll
                for (int u = 0; u < 4; ++u) {
                    acc[r][0][u] += a[r] * w0[u];
                    acc[r][1][u] += a[r] * w1[u];
                }
        }
    }
    // epilogue: scale/bias/leaky + per-thread partial pool over 4 rows
    float hmx[2][4], hsm[2][4];
    #pragma unroll
    for (int h = 0; h < 2; ++h)
        #pragma unroll
        for (int u = 0; u < 4; ++u) { hmx[h][u] = -FLT_MAX; hsm[h][u] = 0.f; }
    #pragma unroll
    for (int h = 0; h < 2; ++h)
        #pragma unroll
        for (int u = 0; u < 4; ++u) {
            int o = col0 + 64 * h + 4 * tx + u;
            float sv = s5[o], bv = b5[o];
            #pragma unroll
            for (int r = 0; r < 4; ++r) {
                float hh = leaky(acc[r][h][u] * sv + bv);
                hmx[h][u] = fmaxf(hmx[h][u], hh);
                hsm[h][u] += hh;
            }
        }
    __syncthreads();
    float* redM = Xi;
    float* redS = Wj;
    #pragma unroll
    for (int h = 0; h < 2; ++h) {
        *(float4*)&redM[ty * 128 + 64 * h + 4 * tx] = *(float4*)hmx[h];
        *(float4*)&redS[ty * 128 + 64 * h + 4 * tx] = *(float4*)hsm[h];
    }
    __syncthreads();
    for (int s = 8; s > 0; s >>= 1) {
        if (ty < s) {
            #pragma unroll
            for (int h = 0; h < 2; ++h) {
                int c = 64 * h + 4 * tx;
                float m0[4], m1[4], s0[4], s1[4];
                *(float4*)m0 = *(float4*)&redM[ty * 128 + c];
                *(float4*)m1 = *(float4*)&redM[(ty + s) * 128 + c];
                *(float4*)s0 = *(float4*)&redS[ty * 128 + c];
                *(float4*)s1 = *(float4*)&redS[(ty + s) * 128 + c];
                #pragma unroll
                for (int u = 0; u < 4; ++u) { m0[u] = fmaxf(m0[u], m1[u]); s0[u] += s1[u]; }
                *(float4*)&redM[ty * 128 + c] = *(float4*)m0;
                *(float4*)&redS[ty * 128 + c] = *(float4*)s0;
            }
        }
        __syncthreads();
    }
    if (ty == 0) {
        #pragma unroll
        for (int h = 0; h < 2; ++h) {
            int c = 64 * h + 4 * tx;
            size_t o = ((size_t)b * 32 + tileInB) * 1024 + col0 + c;
            *(float4*)&pmax[o] = *(float4*)&redM[c];
            *(float4*)&psum[o] = *(float4*)&redS[c];
        }
    }
}

__global__ void k_poolreduce(const float* __restrict__ pmax, const float* __restrict__ psum,
                             float* __restrict__ pooled) {
    int i = blockIdx.x * 256 + threadIdx.x;
    if (i >= BB * 1024) return;
    int b = i / 1024, o = i % 1024;
    float mx = -FLT_MAX, sm = 0.f;
    for (int ch = 0; ch < 32; ++ch) {
        mx = fmaxf(mx, pmax[((size_t)b * 32 + ch) * 1024 + o]);
        sm += psum[((size_t)b * 32 + ch) * 1024 + o];
    }
    pooled[(size_t)b * 2048 + o] = mx;
    pooled[(size_t)b * 2048 + 1024 + o] = sm / (float)NN;
}

// ---------- FC: wave-per-output, coalesced float4 weight reads, shfl reduce ----------
template<int CI, bool SCALE, bool RELU>
__global__ __launch_bounds__(256) void k_fcw(const float* __restrict__ in,
                                             const float* __restrict__ w,
                                             const float* __restrict__ sc,
                                             const float* __restrict__ bi,
                                             float* __restrict__ out, int CO) {
    int wv = (blockIdx.x << 2) + (threadIdx.x >> 6);   // global wave id = b*CO + o
    int lane = threadIdx.x & 63;
    int o = wv % CO, b = wv / CO;
    const float* ir = in + (size_t)b * CI;
    const float* wr = w + (size_t)o * CI;
    float acc = 0.f;
    #pragma unroll
    for (int q = 0; q < CI / 256; ++q) {
        int ofs = q * 256 + 4 * lane;
        float4 wv4 = *(const float4*)(wr + ofs);
        float4 iv4 = *(const float4*)(ir + ofs);
        acc += wv4.x * iv4.x + wv4.y * iv4.y + wv4.z * iv4.z + wv4.w * iv4.w;
    }
    #pragma unroll
    for (int s = 1; s < 64; s <<= 1) acc += __shfl_xor(acc, s);
    if (lane == 0) {
        float v = SCALE ? (acc * sc[o] + bi[o]) : (acc + bi[o]);
        if (RELU) v = fmaxf(v, 0.f);
        out[wv] = v;
    }
}

extern "C" void kernel_launch(void* const* d_in, const int* in_sizes, int n_in,
                              void* d_out, int out_size, void* d_ws, size_t ws_size,
                              hipStream_t stream) {
    const float* x    = (const float*)d_in[0];
    const float* w1   = (const float*)d_in[1];
    const float* s1   = (const float*)d_in[2];
    const float* b1   = (const float*)d_in[3];
    const float* w2   = (const float*)d_in[4];
    const float* s2   = (const float*)d_in[5];
    const float* b2   = (const float*)d_in[6];
    const float* w3   = (const float*)d_in[7];
    const float* s3   = (const float*)d_in[8];
    const float* b3   = (const float*)d_in[9];
    const float* w4   = (const float*)d_in[10];
    const float* s4   = (const float*)d_in[11];
    const float* b4   = (const float*)d_in[12];
    const float* w5   = (const float*)d_in[13];
    const float* s5   = (const float*)d_in[14];
    const float* b5   = (const float*)d_in[15];
    const float* fc1w = (const float*)d_in[16];
    const float* s6   = (const float*)d_in[17];
    const float* b6   = (const float*)d_in[18];
    const float* fc2w = (const float*)d_in[19];
    const float* s7   = (const float*)d_in[20];
    const float* b7   = (const float*)d_in[21];
    const float* fc3w = (const float*)d_in[22];
    const float* fc3b = (const float*)d_in[23];
    float* out = (float*)d_out;

    char* ws = (char*)d_ws;
    size_t off = 0;
    auto alloc = [&](size_t bytes) {
        void* p = ws + off;
        off = (off + bytes + 255) & ~(size_t)255;
        return p;
    };
    float* xt   = (float*)alloc((size_t)BB * NN * 3 * 4);
    float* xcat = (float*)alloc((size_t)BB * NN * 512 * 4);
    int*   idx  = (int*)  alloc((size_t)BB * NN * KNN * 4);
    float* xx   = (float*)alloc((size_t)BB * NN * 4);
    float* wtA1 = (float*)alloc(3 * 64 * 4);
    float* wtD1 = (float*)alloc(3 * 64 * 4);
    float* wtA2 = (float*)alloc(64 * 64 * 4);
    float* wtD2 = (float*)alloc(64 * 64 * 4);
    float* wtA3 = (float*)alloc(64 * 128 * 4);
    float* wtD3 = (float*)alloc(64 * 128 * 4);
    float* wtA4 = (float*)alloc(128 * 256 * 4);
    float* wtD4 = (float*)alloc(128 * 256 * 4);
    size_t base_end = off;

    // UNION region: D (dist phase) / Y+C2 (transform phase) / head buffers
    const size_t D1 = (size_t)NN * NN * 4;
    size_t avail = ws_size > base_end ? ws_size - base_end : 0;
    int nbD = (int)(avail / D1);
    if (nbD < 1) nbD = 1;
    if (nbD > BB) nbD = BB;
    char* uni = ws + base_end;
    float* D      = (float*)uni;
    float* w5t    = (float*)uni;
    float* pmax   = w5t + 512 * 1024;
    float* psum   = pmax + (size_t)BB * 32 * 1024;
    float* pooled = psum + (size_t)BB * 32 * 1024;
    float* f1     = pooled + (size_t)BB * 2048;
    float* f2     = f1 + (size_t)BB * 512;

    k_transpose_x<<<(BB * NN * 3 + 255) / 256, 256, 0, stream>>>(x, xt);
    k_wpair<<<(64 * 3 + 255) / 256, 256, 0, stream>>>(w1, wtA1, wtD1, 64, 3);
    k_wpair<<<(64 * 64 + 255) / 256, 256, 0, stream>>>(w2, wtA2, wtD2, 64, 64);
    k_wpair<<<(128 * 64 + 255) / 256, 256, 0, stream>>>(w3, wtA3, wtD3, 128, 64);
    k_wpair<<<(256 * 128 + 255) / 256, 256, 0, stream>>>(w4, wtA4, wtD4, 256, 128);

    auto layer = [&](auto cTag, auto coTag, const float* F, int FS,
                     const float* wtA, const float* wtD,
                     const float* sc, const float* bi, float* outp) {
        constexpr int C  = decltype(cTag)::value;
        constexpr int CO = decltype(coTag)::value;
        k_xx<C><<<(BB * NN + 255) / 256, 256, 0, stream>>>(F, FS, xx);
        for (int b0 = 0; b0 < BB; b0 += nbD) {
            int nb = BB - b0 < nbD ? BB - b0 : nbD;
            k_dist<C><<<nb * 1024, 256, 0, stream>>>(F, FS, xx, b0, D);
            k_select<<<nb * 512, 256, 0, stream>>>(D, idx, b0);
        }
        size_t ypb = (size_t)NN * CO * 4;
        int nbY = (int)(avail / (2 * ypb));
        if (nbY < 1) nbY = 1;
        if (nbY > BB) nbY = BB;
        for (int b0 = 0; b0 < BB; b0 += nbY) {
            int nb = BB - b0 < nbY ? BB - b0 : nbY;
            float* Yc  = (float*)uni;
            float* C2c = Yc + (size_t)nb * NN * CO;
            dim3 g((nb * NN) / 64, CO / 64);
            k_gemm_pair<C, CO><<<g, 256, 0, stream>>>(F, FS, b0, wtA, wtD, Yc, C2c);
            constexpr int PPB = 4 * (64 / (CO / 4));
            k_gather<CO><<<(nb * NN) / PPB, 256, 0, stream>>>(Yc, C2c, idx, sc, bi, outp, 512, b0);
        }
    };

    layer(std::integral_constant<int, 3>{},   std::integral_constant<int, 64>{},  xt,         3,   wtA1, wtD1, s1, b1, xcat + 0);
    layer(std::integral_constant<int, 64>{},  std::integral_constant<int, 64>{},  xcat + 0,   512, wtA2, wtD2, s2, b2, xcat + 64);
    layer(std::integral_constant<int, 64>{},  std::integral_constant<int, 128>{}, xcat + 64,  512, wtA3, wtD3, s3, b3, xcat + 128);
    layer(std::integral_constant<int, 128>{}, std::integral_constant<int, 256>{}, xcat + 128, 512, wtA4, wtD4, s4, b4, xcat + 256);

    // head (union region now holds w5t/pmax/psum/pooled/f1/f2)
    dim3 gt(1024 / 64, 512 / 64);
    k_transpose_w_tiled<<<gt, 256, 0, stream>>>(w5, w5t, 1024, 512);
    dim3 g5((BB * NN) / 64, 1024 / 128);
    k_conv5<<<g5, 256, 0, stream>>>(xcat, w5t, s5, b5, pmax, psum);
    k_poolreduce<<<(BB * 1024 + 255) / 256, 256, 0, stream>>>(pmax, psum, pooled);
    k_fcw<2048, true,  true ><<<(BB * 512) / 4, 256, 0, stream>>>(pooled, fc1w, s6, b6, f1, 512);
    k_fcw<512,  true,  true ><<<(BB * 256) / 4, 256, 0, stream>>>(f1, fc2w, s7, b7, f2, 256);
    k_fcw<256,  false, false><<<(BB * 40)  / 4, 256, 0, stream>>>(f2, fc3w, nullptr, fc3b, out, 40);
}

// Round 6
// 1068.085 us; speedup vs baseline: 6.3571x; 1.0439x over previous
//
#include <hip/hip_runtime.h>
#include <float.h>
#include <type_traits>

#define BB 8
#define NN 2048
#define KNN 20

__device__ __forceinline__ float leaky(float v) { return fmaxf(v, 0.2f * v); }

// ---------- transpose x (B,3,N) -> xt (B,N,3) ----------
__global__ void k_transpose_x(const float* __restrict__ x, float* __restrict__ xt) {
    int i = blockIdx.x * 256 + threadIdx.x;
    if (i >= BB * NN * 3) return;
    int c = i % 3; int n = (i / 3) % NN; int b = i / (3 * NN);
    xt[i] = x[((size_t)b * 3 + c) * NN + n];
}

// ---------- LDS-tiled transpose w (CO,CI) -> wt (CI,CO), 64x64 tiles ----------
__global__ __launch_bounds__(256) void k_transpose_w_tiled(const float* __restrict__ w,
                                                           float* __restrict__ wt,
                                                           int CO, int CI) {
    __shared__ float tile[64][65];
    int o0 = blockIdx.x * 64;
    int c0 = blockIdx.y * 64;
    int tid = threadIdx.x;
    for (int i = tid; i < 64 * 64; i += 256) {
        int r = i >> 6, c = i & 63;
        tile[r][c] = w[(size_t)(o0 + r) * CI + c0 + c];
    }
    __syncthreads();
    for (int i = tid; i < 64 * 64; i += 256) {
        int cc = i >> 6, oo = i & 63;
        wt[(size_t)(c0 + cc) * CO + o0 + oo] = tile[oo][cc];
    }
}

// ---------- edgeconv weight split: w (CO, 2*CI) -> wtA (CI,CO), wtD (CI,CO) ----------
__global__ void k_wpair(const float* __restrict__ w, float* __restrict__ wtA,
                        float* __restrict__ wtD, int CO, int CI) {
    int i = blockIdx.x * 256 + threadIdx.x;
    if (i >= CO * CI) return;
    int o = i / CI, c = i % CI;
    float a = w[(size_t)o * 2 * CI + c];
    float bb = w[(size_t)o * 2 * CI + CI + c];
    wtA[c * CO + o] = a;
    wtD[c * CO + o] = bb - a;
}

// ---------- squared norms per point ----------
template<int C>
__global__ void k_xx(const float* __restrict__ F, int FS, float* __restrict__ xx) {
    int i = blockIdx.x * 256 + threadIdx.x;
    if (i >= BB * NN) return;
    const float* r = F + (size_t)i * FS;
    float s = 0.f;
    #pragma unroll
    for (int c = 0; c < C; ++c) { float v = r[c]; s += v * v; }
    xx[i] = s;
}

// ---------- distance matrix, small-C (C=3): 64x64 tile ----------
template<int C>
__global__ __launch_bounds__(256) void k_dist(const float* __restrict__ F, int FS,
                                              const float* __restrict__ xx, int b0,
                                              float* __restrict__ D) {
    __shared__ __align__(16) float Xi[C * 64];
    __shared__ __align__(16) float Xj[C * 64];
    int tid = threadIdx.x;
    int bl = blockIdx.x >> 10;
    int t  = blockIdx.x & 1023;
    int i0 = (t >> 5) * 64, j0 = (t & 31) * 64;
    int b = b0 + bl;
    const float* Fb = F + (size_t)b * NN * FS;
    int ty = tid >> 4, tx = tid & 15;
    float acc[4][4] = {};
    for (int k = tid; k < 64 * C; k += 256) {
        int r = k & 63, c = k >> 6;
        Xi[c * 64 + r] = Fb[(size_t)(i0 + r) * FS + c];
        Xj[c * 64 + r] = Fb[(size_t)(j0 + r) * FS + c];
    }
    __syncthreads();
    for (int c = 0; c < C; ++c) {
        float a[4], bv[4];
        *(float4*)a  = *(const float4*)&Xi[c * 64 + 4 * ty];
        *(float4*)bv = *(const float4*)&Xj[c * 64 + 4 * tx];
        #pragma unroll
        for (int r = 0; r < 4; ++r)
            #pragma unroll
            for (int s = 0; s < 4; ++s) acc[r][s] += a[r] * bv[s];
    }
    const float* xxb = xx + (size_t)b * NN;
    float xxi[4], xxj[4];
    #pragma unroll
    for (int r = 0; r < 4; ++r) xxi[r] = xxb[i0 + 4 * ty + r];
    #pragma unroll
    for (int s = 0; s < 4; ++s) xxj[s] = xxb[j0 + 4 * tx + s];
    float* Dp = D + (size_t)bl * NN * NN;
    #pragma unroll
    for (int r = 0; r < 4; ++r) {
        float ov[4];
        #pragma unroll
        for (int s = 0; s < 4; ++s) ov[s] = 2.f * acc[r][s] - xxi[r] - xxj[s];
        *(float4*)(Dp + (size_t)(i0 + 4 * ty + r) * NN + j0 + 4 * tx) = *(float4*)ov;
    }
}

// ---------- distance matrix, big-C (64/128): 128x128 tile, 8x8 micro-tile ----------
// All LDS reads at 16B lane stride (row/col groups {4*t, 64+4*t}) -> 2-way = free.
template<int C>
__global__ __launch_bounds__(256) void k_dist128(const float* __restrict__ F, int FS,
                                                 const float* __restrict__ xx, int b0,
                                                 float* __restrict__ D) {
    constexpr int NCH = C / 32;
    __shared__ __align__(16) float Xi[32 * 128];
    __shared__ __align__(16) float Xj[32 * 128];
    int tid = threadIdx.x;
    int ty = tid >> 4, tx = tid & 15;
    int bl = blockIdx.x >> 8;            // 256 tiles per batch (16x16)
    int t  = blockIdx.x & 255;
    int i0 = (t >> 4) * 128, j0 = (t & 15) * 128;
    int b = b0 + bl;
    const float* Fb = F + (size_t)b * NN * FS;
    float acc[8][8] = {};
    for (int ch = 0; ch < NCH; ++ch) {
        int cb = ch * 32;
        if (ch) __syncthreads();
        for (int k = tid; k < 128 * 8; k += 256) {
            int r = k & 127, cc = k >> 7;
            float vi[4], vj[4];
            *(float4*)vi = *(const float4*)(Fb + (size_t)(i0 + r) * FS + cb + 4 * cc);
            *(float4*)vj = *(const float4*)(Fb + (size_t)(j0 + r) * FS + cb + 4 * cc);
            #pragma unroll
            for (int u = 0; u < 4; ++u) {
                Xi[(4 * cc + u) * 128 + r] = vi[u];
                Xj[(4 * cc + u) * 128 + r] = vj[u];
            }
        }
        __syncthreads();
        for (int c = 0; c < 32; ++c) {
            float a0[4], a1[4], w0[4], w1[4];
            *(float4*)a0 = *(const float4*)&Xi[c * 128 + 4 * ty];
            *(float4*)a1 = *(const float4*)&Xi[c * 128 + 64 + 4 * ty];
            *(float4*)w0 = *(const float4*)&Xj[c * 128 + 4 * tx];
            *(float4*)w1 = *(const float4*)&Xj[c * 128 + 64 + 4 * tx];
            #pragma unroll
            for (int r = 0; r < 4; ++r)
                #pragma unroll
                for (int s = 0; s < 4; ++s) {
                    acc[r][s]         += a0[r] * w0[s];
                    acc[r][4 + s]     += a0[r] * w1[s];
                    acc[4 + r][s]     += a1[r] * w0[s];
                    acc[4 + r][4 + s] += a1[r] * w1[s];
                }
        }
    }
    const float* xxb = xx + (size_t)b * NN;
    float xxi[8], xxj[8];
    #pragma unroll
    for (int r = 0; r < 4; ++r) {
        xxi[r]     = xxb[i0 + 4 * ty + r];
        xxi[4 + r] = xxb[i0 + 64 + 4 * ty + r];
        xxj[r]     = xxb[j0 + 4 * tx + r];
        xxj[4 + r] = xxb[j0 + 64 + 4 * tx + r];
    }
    float* Dp = D + (size_t)bl * NN * NN;
    #pragma unroll
    for (int r = 0; r < 8; ++r) {
        int row = i0 + (r < 4 ? 4 * ty + r : 64 + 4 * ty + (r - 4));
        float ov0[4], ov1[4];
        #pragma unroll
        for (int s = 0; s < 4; ++s) {
            ov0[s] = 2.f * acc[r][s]     - xxi[r] - xxj[s];
            ov1[s] = 2.f * acc[r][4 + s] - xxi[r] - xxj[4 + s];
        }
        *(float4*)(Dp + (size_t)row * NN + j0 + 4 * tx)      = *(float4*)ov0;
        *(float4*)(Dp + (size_t)row * NN + j0 + 64 + 4 * tx) = *(float4*)ov1;
    }
}

// ---------- top-20 selection: one wave per query, row in registers ----------
__global__ __launch_bounds__(256) void k_select(const float* __restrict__ D,
                                                int* __restrict__ idxo, int b0) {
    int tid = threadIdx.x;
    int lane = tid & 63;
    int w = (blockIdx.x << 2) + (tid >> 6);
    int bl = w / NN, n = w % NN;
    const float* row = D + (size_t)w * NN;
    float d[32];
    #pragma unroll
    for (int q = 0; q < 8; ++q)
        *(float4*)&d[4 * q] = *(const float4*)(row + 4 * lane + 256 * q);
    float bv = d[0]; int bj = 0;
    #pragma unroll
    for (int j = 1; j < 32; ++j) if (d[j] > bv) { bv = d[j]; bj = j; }
    int* op = idxo + ((size_t)(b0 + bl) * NN + n) * KNN;
    for (int k = 0; k < KNN; ++k) {
        float rv = bv;
        int rm = 4 * lane + 256 * (bj >> 2) + (bj & 3);
        #pragma unroll
        for (int s = 1; s < 64; s <<= 1) {
            float ov = __shfl_xor(rv, s);
            int om = __shfl_xor(rm, s);
            if (ov > rv || (ov == rv && om < rm)) { rv = ov; rm = om; }
        }
        if (lane == 0) op[k] = rm;
        if (((rm >> 2) & 63) == lane) {
            int oj = ((rm >> 8) << 2) | (rm & 3);
            #pragma unroll
            for (int j = 0; j < 32; ++j) if (j == oj) d[j] = -FLT_MAX;
            bv = d[0]; bj = 0;
            #pragma unroll
            for (int j = 1; j < 32; ++j) if (d[j] > bv) { bv = d[j]; bj = j; }
        }
    }
}

// ---------- pair GEMM: Y = F*wtA, C2 = F*wtD  (64 rows x 64 cols per block) ----------
template<int CIN, int COUT>
__global__ __launch_bounds__(256) void k_gemm_pair(const float* __restrict__ F, int FS, int b0,
    const float* __restrict__ wtA, const float* __restrict__ wtD,
    float* __restrict__ Y, float* __restrict__ C2) {
    constexpr int CCH = (CIN >= 32) ? 32 : CIN;
    constexpr int NCH = CIN / CCH;
    __shared__ __align__(16) float Xi[CCH * 64];
    __shared__ __align__(16) float Wa[CCH * 64];
    __shared__ __align__(16) float Wd[CCH * 64];
    int tid = threadIdx.x;
    int r0 = blockIdx.x * 64;
    int c0 = blockIdx.y * 64;
    int b = b0 + r0 / NN;
    int n0 = r0 % NN;
    const float* Fb = F + ((size_t)b * NN + n0) * FS;
    int ty = tid >> 4, tx = tid & 15;
    float accY[4][4] = {}, accD[4][4] = {};
    for (int ch = 0; ch < NCH; ++ch) {
        int cb = ch * CCH;
        if (ch) __syncthreads();
        if constexpr (CCH % 4 == 0) {
            for (int t = tid; t < 64 * (CCH / 4); t += 256) {
                int r = t & 63, cc = t >> 6;
                float v[4];
                *(float4*)v = *(const float4*)(Fb + (size_t)r * FS + cb + 4 * cc);
                #pragma unroll
                for (int u = 0; u < 4; ++u) Xi[(4 * cc + u) * 64 + r] = v[u];
            }
            for (int t = tid; t < CCH * 16; t += 256) {
                int c = t >> 4, q = t & 15;
                *(float4*)&Wa[c * 64 + 4 * q] = *(const float4*)(wtA + (size_t)(cb + c) * COUT + c0 + 4 * q);
                *(float4*)&Wd[c * 64 + 4 * q] = *(const float4*)(wtD + (size_t)(cb + c) * COUT + c0 + 4 * q);
            }
        } else {
            for (int t = tid; t < 64 * CCH; t += 256) {
                int r = t & 63, c = t >> 6;
                Xi[c * 64 + r] = Fb[(size_t)r * FS + cb + c];
            }
            for (int t = tid; t < CCH * 64; t += 256) {
                int col = t & 63, c = t >> 6;
                Wa[c * 64 + col] = wtA[(size_t)(cb + c) * COUT + c0 + col];
                Wd[c * 64 + col] = wtD[(size_t)(cb + c) * COUT + c0 + col];
            }
        }
        __syncthreads();
        for (int c = 0; c < CCH; ++c) {
            float a[4], wa[4], wd[4];
            *(float4*)a  = *(const float4*)&Xi[c * 64 + 4 * ty];
            *(float4*)wa = *(const float4*)&Wa[c * 64 + 4 * tx];
            *(float4*)wd = *(const float4*)&Wd[c * 64 + 4 * tx];
            #pragma unroll
            for (int r = 0; r < 4; ++r)
                #pragma unroll
                for (int s = 0; s < 4; ++s) {
                    accY[r][s] += a[r] * wa[s];
                    accD[r][s] += a[r] * wd[s];
                }
        }
    }
    #pragma unroll
    for (int r = 0; r < 4; ++r) {
        size_t ro = (size_t)(r0 + 4 * ty + r) * COUT + c0 + 4 * tx;
        *(float4*)(Y  + ro) = *(float4*)accY[r];
        *(float4*)(C2 + ro) = *(float4*)accD[r];
    }
}

// ---------- gather-max: out[p][o] = max_k leaky((Y[idx[p][k]][o] + C2[p][o])*s + b) ----------
template<int COUT>
__global__ __launch_bounds__(256) void k_gather(const float* __restrict__ Y,
    const float* __restrict__ C2, const int* __restrict__ idx,
    const float* __restrict__ sc, const float* __restrict__ bi,
    float* __restrict__ out, int OS, int b0) {
    constexpr int LPP = COUT / 4;
    constexpr int PPW = 64 / LPP;
    constexpr int PPB = 4 * PPW;
    int tid = threadIdx.x;
    int lane = tid & 63, wv = tid >> 6;
    int pl = blockIdx.x * PPB + wv * PPW + lane / LPP;
    int bl = pl / NN, n = pl % NN;
    int o0 = 4 * (lane % LPP);
    float c2[4], s4[4], b4[4];
    *(float4*)c2 = *(const float4*)(C2 + (size_t)pl * COUT + o0);
    *(float4*)s4 = *(const float4*)(sc + o0);
    *(float4*)b4 = *(const float4*)(bi + o0);
    const int* ip = idx + ((size_t)(b0 + bl) * NN + n) * KNN;
    const float* Yb = Y + (size_t)bl * NN * COUT;
    float mx[4] = {-FLT_MAX, -FLT_MAX, -FLT_MAX, -FLT_MAX};
    for (int k = 0; k < KNN; ++k) {
        int m = ip[k];
        float y[4];
        *(float4*)y = *(const float4*)(Yb + (size_t)m * COUT + o0);
        #pragma unroll
        for (int u = 0; u < 4; ++u) {
            float v = (y[u] + c2[u]) * s4[u] + b4[u];
            mx[u] = fmaxf(mx[u], leaky(v));
        }
    }
    float* op = out + ((size_t)(b0 + bl) * NN + n) * OS + o0;
    *(float4*)op = *(float4*)mx;
}

// ---------- conv5: 16384x1024x512 GEMM, 128x128 tile, 8x8 micro-tile,
// fused partial max/sum pooling. All LDS reads at 16B lane stride. ----------
__global__ __launch_bounds__(256) void k_conv5(const float* __restrict__ xcat,
    const float* __restrict__ w5t, const float* __restrict__ s5, const float* __restrict__ b5,
    float* __restrict__ pmax, float* __restrict__ psum) {
    __shared__ __align__(16) float Xi[32 * 128];   // 16KB [c][row]
    __shared__ __align__(16) float Wj[32 * 128];   // 16KB [c][col]
    int tid = threadIdx.x;
    int ty = tid >> 4, tx = tid & 15;
    int r0 = blockIdx.x * 128;
    int col0 = blockIdx.y * 128;
    int b = r0 / NN, tileInB = (r0 % NN) / 128;
    const float* Fb = xcat + (size_t)r0 * 512;
    float acc[8][8] = {};
    for (int ch = 0; ch < 16; ++ch) {
        int cb = ch * 32;
        if (ch) __syncthreads();
        for (int t = tid; t < 128 * 8; t += 256) {
            int r = t & 127, cc = t >> 7;
            float v[4];
            *(float4*)v = *(const float4*)(Fb + (size_t)r * 512 + cb + 4 * cc);
            #pragma unroll
            for (int u = 0; u < 4; ++u) Xi[(4 * cc + u) * 128 + r] = v[u];
        }
        for (int t = tid; t < 32 * 32; t += 256) {
            int c = t >> 5, q = t & 31;
            *(float4*)&Wj[c * 128 + 4 * q] = *(const float4*)(w5t + (size_t)(cb + c) * 1024 + col0 + 4 * q);
        }
        __syncthreads();
        for (int c = 0; c < 32; ++c) {
            float a0[4], a1[4], w0[4], w1[4];
            *(float4*)a0 = *(const float4*)&Xi[c * 128 + 4 * ty];
            *(float4*)a1 = *(const float4*)&Xi[c * 128 + 64 + 4 * ty];
            *(float4*)w0 = *(const float4*)&Wj[c * 128 + 4 * tx];
            *(float4*)w1 = *(const float4*)&Wj[c * 128 + 64 + 4 * tx];
            #pragma unroll
            for (int r = 0; r < 4; ++r)
                #pragma unroll
                for (int u = 0; u < 4; ++u) {
                    acc[r][u]         += a0[r] * w0[u];
                    acc[r][4 + u]     += a0[r] * w1[u];
                    acc[4 + r][u]     += a1[r] * w0[u];
                    acc[4 + r][4 + u] += a1[r] * w1[u];
                }
        }
    }
    // epilogue: scale/bias/leaky + per-thread partial pool over its 8 rows
    float hmx[2][4], hsm[2][4];
    #pragma unroll
    for (int h = 0; h < 2; ++h)
        #pragma unroll
        for (int u = 0; u < 4; ++u) { hmx[h][u] = -FLT_MAX; hsm[h][u] = 0.f; }
    #pragma unroll
    for (int h = 0; h < 2; ++h)
        #pragma unroll
        for (int u = 0; u < 4; ++u) {
            int o = col0 + 64 * h + 4 * tx + u;
            float sv = s5[o], bv = b5[o];
            #pragma unroll
            for (int r = 0; r < 8; ++r) {
                float hh = leaky(acc[r][4 * h + u] * sv + bv);
                hmx[h][u] = fmaxf(hmx[h][u], hh);
                hsm[h][u] += hh;
            }
        }
    __syncthreads();
    float* redM = Xi;
    float* redS = Wj;
    #pragma unroll
    for (int h = 0; h < 2; ++h) {
        *(float4*)&redM[ty * 128 + 64 * h + 4 * tx] = *(float4*)hmx[h];
        *(float4*)&redS[ty * 128 + 64 * h + 4 * tx] = *(float4*)hsm[h];
    }
    __syncthreads();
    for (int s = 8; s > 0; s >>= 1) {
        if (ty < s) {
            #pragma unroll
            for (int h = 0; h < 2; ++h) {
                int c = 64 * h + 4 * tx;
                float m0[4], m1[4], s0[4], s1[4];
                *(float4*)m0 = *(float4*)&redM[ty * 128 + c];
                *(float4*)m1 = *(float4*)&redM[(ty + s) * 128 + c];
                *(float4*)s0 = *(float4*)&redS[ty * 128 + c];
                *(float4*)s1 = *(float4*)&redS[(ty + s) * 128 + c];
                #pragma unroll
                for (int u = 0; u < 4; ++u) { m0[u] = fmaxf(m0[u], m1[u]); s0[u] += s1[u]; }
                *(float4*)&redM[ty * 128 + c] = *(float4*)m0;
                *(float4*)&redS[ty * 128 + c] = *(float4*)s0;
            }
        }
        __syncthreads();
    }
    if (ty == 0) {
        #pragma unroll
        for (int h = 0; h < 2; ++h) {
            int c = 64 * h + 4 * tx;
            size_t o = ((size_t)b * 16 + tileInB) * 1024 + col0 + c;
            *(float4*)&pmax[o] = *(float4*)&redM[c];
            *(float4*)&psum[o] = *(float4*)&redS[c];
        }
    }
}

__global__ void k_poolreduce(const float* __restrict__ pmax, const float* __restrict__ psum,
                             float* __restrict__ pooled) {
    int i = blockIdx.x * 256 + threadIdx.x;
    if (i >= BB * 1024) return;
    int b = i / 1024, o = i % 1024;
    float mx = -FLT_MAX, sm = 0.f;
    for (int ch = 0; ch < 16; ++ch) {
        mx = fmaxf(mx, pmax[((size_t)b * 16 + ch) * 1024 + o]);
        sm += psum[((size_t)b * 16 + ch) * 1024 + o];
    }
    pooled[(size_t)b * 2048 + o] = mx;
    pooled[(size_t)b * 2048 + 1024 + o] = sm / (float)NN;
}

// ---------- FC: wave-per-output, coalesced float4 weight reads, shfl reduce ----------
template<int CI, bool SCALE, bool RELU>
__global__ __launch_bounds__(256) void k_fcw(const float* __restrict__ in,
                                             const float* __restrict__ w,
                                             const float* __restrict__ sc,
                                             const float* __restrict__ bi,
                                             float* __restrict__ out, int CO) {
    int wv = (blockIdx.x << 2) + (threadIdx.x >> 6);   // global wave id = b*CO + o
    int lane = threadIdx.x & 63;
    int o = wv % CO, b = wv / CO;
    const float* ir = in + (size_t)b * CI;
    const float* wr = w + (size_t)o * CI;
    float acc = 0.f;
    #pragma unroll
    for (int q = 0; q < CI / 256; ++q) {
        int ofs = q * 256 + 4 * lane;
        float4 wv4 = *(const float4*)(wr + ofs);
        float4 iv4 = *(const float4*)(ir + ofs);
        acc += wv4.x * iv4.x + wv4.y * iv4.y + wv4.z * iv4.z + wv4.w * iv4.w;
    }
    #pragma unroll
    for (int s = 1; s < 64; s <<= 1) acc += __shfl_xor(acc, s);
    if (lane == 0) {
        float v = SCALE ? (acc * sc[o] + bi[o]) : (acc + bi[o]);
        if (RELU) v = fmaxf(v, 0.f);
        out[wv] = v;
    }
}

extern "C" void kernel_launch(void* const* d_in, const int* in_sizes, int n_in,
                              void* d_out, int out_size, void* d_ws, size_t ws_size,
                              hipStream_t stream) {
    const float* x    = (const float*)d_in[0];
    const float* w1   = (const float*)d_in[1];
    const float* s1   = (const float*)d_in[2];
    const float* b1   = (const float*)d_in[3];
    const float* w2   = (const float*)d_in[4];
    const float* s2   = (const float*)d_in[5];
    const float* b2   = (const float*)d_in[6];
    const float* w3   = (const float*)d_in[7];
    const float* s3   = (const float*)d_in[8];
    const float* b3   = (const float*)d_in[9];
    const float* w4   = (const float*)d_in[10];
    const float* s4   = (const float*)d_in[11];
    const float* b4   = (const float*)d_in[12];
    const float* w5   = (const float*)d_in[13];
    const float* s5   = (const float*)d_in[14];
    const float* b5   = (const float*)d_in[15];
    const float* fc1w = (const float*)d_in[16];
    const float* s6   = (const float*)d_in[17];
    const float* b6   = (const float*)d_in[18];
    const float* fc2w = (const float*)d_in[19];
    const float* s7   = (const float*)d_in[20];
    const float* b7   = (const float*)d_in[21];
    const float* fc3w = (const float*)d_in[22];
    const float* fc3b = (const float*)d_in[23];
    float* out = (float*)d_out;

    char* ws = (char*)d_ws;
    size_t off = 0;
    auto alloc = [&](size_t bytes) {
        void* p = ws + off;
        off = (off + bytes + 255) & ~(size_t)255;
        return p;
    };
    float* xt   = (float*)alloc((size_t)BB * NN * 3 * 4);
    float* xcat = (float*)alloc((size_t)BB * NN * 512 * 4);
    int*   idx  = (int*)  alloc((size_t)BB * NN * KNN * 4);
    float* xx   = (float*)alloc((size_t)BB * NN * 4);
    float* wtA1 = (float*)alloc(3 * 64 * 4);
    float* wtD1 = (float*)alloc(3 * 64 * 4);
    float* wtA2 = (float*)alloc(64 * 64 * 4);
    float* wtD2 = (float*)alloc(64 * 64 * 4);
    float* wtA3 = (float*)alloc(64 * 128 * 4);
    float* wtD3 = (float*)alloc(64 * 128 * 4);
    float* wtA4 = (float*)alloc(128 * 256 * 4);
    float* wtD4 = (float*)alloc(128 * 256 * 4);
    size_t base_end = off;

    // UNION region: D (dist phase) / Y+C2 (transform phase) / head buffers
    const size_t D1 = (size_t)NN * NN * 4;
    size_t avail = ws_size > base_end ? ws_size - base_end : 0;
    int nbD = (int)(avail / D1);
    if (nbD < 1) nbD = 1;
    if (nbD > BB) nbD = BB;
    char* uni = ws + base_end;
    float* D      = (float*)uni;
    float* w5t    = (float*)uni;
    float* pmax   = w5t + 512 * 1024;
    float* psum   = pmax + (size_t)BB * 16 * 1024;
    float* pooled = psum + (size_t)BB * 16 * 1024;
    float* f1     = pooled + (size_t)BB * 2048;
    float* f2     = f1 + (size_t)BB * 512;

    k_transpose_x<<<(BB * NN * 3 + 255) / 256, 256, 0, stream>>>(x, xt);
    k_wpair<<<(64 * 3 + 255) / 256, 256, 0, stream>>>(w1, wtA1, wtD1, 64, 3);
    k_wpair<<<(64 * 64 + 255) / 256, 256, 0, stream>>>(w2, wtA2, wtD2, 64, 64);
    k_wpair<<<(128 * 64 + 255) / 256, 256, 0, stream>>>(w3, wtA3, wtD3, 128, 64);
    k_wpair<<<(256 * 128 + 255) / 256, 256, 0, stream>>>(w4, wtA4, wtD4, 256, 128);

    auto layer = [&](auto cTag, auto coTag, const float* F, int FS,
                     const float* wtA, const float* wtD,
                     const float* sc, const float* bi, float* outp) {
        constexpr int C  = decltype(cTag)::value;
        constexpr int CO = decltype(coTag)::value;
        k_xx<C><<<(BB * NN + 255) / 256, 256, 0, stream>>>(F, FS, xx);
        for (int b0 = 0; b0 < BB; b0 += nbD) {
            int nb = BB - b0 < nbD ? BB - b0 : nbD;
            if constexpr (C >= 32) {
                k_dist128<C><<<nb * 256, 256, 0, stream>>>(F, FS, xx, b0, D);
            } else {
                k_dist<C><<<nb * 1024, 256, 0, stream>>>(F, FS, xx, b0, D);
            }
            k_select<<<nb * 512, 256, 0, stream>>>(D, idx, b0);
        }
        size_t ypb = (size_t)NN * CO * 4;
        int nbY = (int)(avail / (2 * ypb));
        if (nbY < 1) nbY = 1;
        if (nbY > BB) nbY = BB;
        for (int b0 = 0; b0 < BB; b0 += nbY) {
            int nb = BB - b0 < nbY ? BB - b0 : nbY;
            float* Yc  = (float*)uni;
            float* C2c = Yc + (size_t)nb * NN * CO;
            dim3 g((nb * NN) / 64, CO / 64);
            k_gemm_pair<C, CO><<<g, 256, 0, stream>>>(F, FS, b0, wtA, wtD, Yc, C2c);
            constexpr int PPB = 4 * (64 / (CO / 4));
            k_gather<CO><<<(nb * NN) / PPB, 256, 0, stream>>>(Yc, C2c, idx, sc, bi, outp, 512, b0);
        }
    };

    layer(std::integral_constant<int, 3>{},   std::integral_constant<int, 64>{},  xt,         3,   wtA1, wtD1, s1, b1, xcat + 0);
    layer(std::integral_constant<int, 64>{},  std::integral_constant<int, 64>{},  xcat + 0,   512, wtA2, wtD2, s2, b2, xcat + 64);
    layer(std::integral_constant<int, 64>{},  std::integral_constant<int, 128>{}, xcat + 64,  512, wtA3, wtD3, s3, b3, xcat + 128);
    layer(std::integral_constant<int, 128>{}, std::integral_constant<int, 256>{}, xcat + 128, 512, wtA4, wtD4, s4, b4, xcat + 256);

    // head (union region now holds w5t/pmax/psum/pooled/f1/f2)
    dim3 gt(1024 / 64, 512 / 64);
    k_transpose_w_tiled<<<gt, 256, 0, stream>>>(w5, w5t, 1024, 512);
    dim3 g5((BB * NN) / 128, 1024 / 128);
    k_conv5<<<g5, 256, 0, stream>>>(xcat, w5t, s5, b5, pmax, psum);
    k_poolreduce<<<(BB * 1024 + 255) / 256, 256, 0, stream>>>(pmax, psum, pooled);
    k_fcw<2048, true,  true ><<<(BB * 512) / 4, 256, 0, stream>>>(pooled, fc1w, s6, b6, f1, 512);
    k_fcw<512,  true,  true ><<<(BB * 256) / 4, 256, 0, stream>>>(f1, fc2w, s7, b7, f2, 256);
    k_fcw<256,  false, false><<<(BB * 40)  / 4, 256, 0, stream>>>(f2, fc3w, nullptr, fc3b, out, 40);
}